// Round 5
// baseline (516.705 us; speedup 1.0000x reference)
//
#include <hip/hip_runtime.h>

#define NEG_SLOPE 0.2f

typedef __bf16 bf16x8 __attribute__((ext_vector_type(8)));
typedef float f32x4 __attribute__((ext_vector_type(4)));

__device__ __forceinline__ float eluf(float x) { return x > 0.f ? x : __expf(x) - 1.f; }
__device__ __forceinline__ float lreluf(float x) { return x > 0.f ? x : NEG_SLOPE * x; }

__device__ __forceinline__ void split8(const float4& p, const float4& q, bf16x8& hi, bf16x8& lo) {
  float v[8] = {p.x, p.y, p.z, p.w, q.x, q.y, q.z, q.w};
#pragma unroll
  for (int e = 0; e < 8; ++e) {
    __bf16 h = (__bf16)v[e];
    hi[e] = h;
    lo[e] = (__bf16)(v[e] - (float)h);
  }
}

// ---------------- CSR build ----------------

__global__ __launch_bounds__(256) void k_init(int* __restrict__ deg, int* __restrict__ flag, int N) {
  int i = blockIdx.x * 256 + threadIdx.x;
  if (i < N) deg[i] = 1;  // self-loop
  if (i == 0) *flag = 0;
}

// If edge_index arrived as int64, every odd int32 word is 0 (values < 2^31).
__global__ __launch_bounds__(256) void k_detect(const int* __restrict__ raw, int* __restrict__ flag, int nCheck) {
  int i = blockIdx.x * 256 + threadIdx.x;
  if (i < nCheck && raw[2 * i + 1] != 0) atomicOr(flag, 1);
}

__global__ __launch_bounds__(256) void k_convert(const int* __restrict__ raw, const int* __restrict__ flag,
                                                 int* __restrict__ out, int n) {
  int i = blockIdx.x * 256 + threadIdx.x;
  if (i >= n) return;
  bool is32 = (*flag != 0);
  out[i] = is32 ? raw[i] : raw[2 * i];
}

__global__ __launch_bounds__(256) void k_count(const int* __restrict__ ei, int* __restrict__ deg, int E) {
  int e = blockIdx.x * 256 + threadIdx.x;
  if (e < E) atomicAdd(&deg[ei[E + e]], 1);
}

__global__ __launch_bounds__(256) void k_blocksum(const int* __restrict__ deg, int* __restrict__ bsum, int N) {
  __shared__ int s[256];
  int t = threadIdx.x;
  int i = blockIdx.x * 256 + t;
  s[t] = (i < N) ? deg[i] : 0;
  __syncthreads();
  for (int off = 128; off > 0; off >>= 1) {
    if (t < off) s[t] += s[t + off];
    __syncthreads();
  }
  if (t == 0) bsum[blockIdx.x] = s[0];
}

__global__ __launch_bounds__(512) void k_scan_bsum(const int* __restrict__ bsum, int* __restrict__ boff,
                                                   int nb, int* __restrict__ rowptr, int N) {
  __shared__ int s[512];
  int t = threadIdx.x;
  int v = (t < nb) ? bsum[t] : 0;
  s[t] = v;
  __syncthreads();
  for (int off = 1; off < 512; off <<= 1) {
    int u = (t >= off) ? s[t - off] : 0;
    __syncthreads();
    s[t] += u;
    __syncthreads();
  }
  if (t < nb) boff[t] = s[t] - v;       // exclusive
  if (t == nb - 1) rowptr[N] = s[t];    // total = E + N
}

__global__ __launch_bounds__(256) void k_scan_final(const int* __restrict__ deg, const int* __restrict__ boff,
                                                    int* __restrict__ rowptr, int* __restrict__ cursor, int N) {
  __shared__ int s[256];
  int t = threadIdx.x;
  int i = blockIdx.x * 256 + t;
  int v = (i < N) ? deg[i] : 0;
  s[t] = v;
  __syncthreads();
  for (int off = 1; off < 256; off <<= 1) {
    int u = (t >= off) ? s[t - off] : 0;
    __syncthreads();
    s[t] += u;
    __syncthreads();
  }
  if (i < N) {
    int ex = boff[blockIdx.x] + s[t] - v;
    rowptr[i] = ex;
    cursor[i] = ex;
  }
}

// XCD-sharded CSR fill (see R3): each XCD's csr writes stay in its own L2.
__global__ __launch_bounds__(256) void k_fill_shard(const int* __restrict__ ei, int* __restrict__ cursor,
                                                    int* __restrict__ csr, int E, int N, int CH) {
  const int shard = blockIdx.x & 7;
  const int chunk = blockIdx.x >> 3;
  const int i0 = chunk * CH;
  const int i1 = min(i0 + CH, E + N);
  for (int idx = i0 + (int)threadIdx.x; idx < i1; idx += 256) {
    int d = (idx < E) ? ei[E + idx] : idx - E;
    if (((d >> 13) & 7) != shard) continue;
    int s = (idx < E) ? ei[idx] : idx - E;
    int pos = atomicAdd(&cursor[d], 1);
    csr[pos] = s;
  }
}

// ---------------- layer-1 GEMM: split-bf16 MFMA ----------------

// Pack W1^T into per-lane MFMA B fragments (hi/lo split).
__global__ __launch_bounds__(256) void k_prep_b1(const float* __restrict__ W1, __bf16* __restrict__ bhi,
                                                 __bf16* __restrict__ blo) {
  int idx = blockIdx.x * 256 + threadIdx.x;  // 0 .. 16*4*64*8-1 = 32767
  if (idx >= 16 * 4 * 64 * 8) return;
  int e = idx & 7;
  int lane = (idx >> 3) & 63;
  int nf = (idx >> 9) & 3;
  int ks = idx >> 11;
  int k = ks * 32 + (lane >> 4) * 8 + e;
  int col = nf * 16 + (lane & 15);
  float w = (k < 500) ? W1[(size_t)col * 500 + k] : 0.f;
  __bf16 h = (__bf16)w;
  bhi[idx] = h;
  blo[idx] = (__bf16)(w - (float)h);
}

// C[M x 64] = X[M x 500] * W1^T via 3-term split-bf16 MFMA. Emits fp32 + bf16 C.
// 4 waves/block, each wave = 2 row-tiles (32 rows). Branch-free hot path:
// ks=0..14 unguarded (max k = 479 < 500), ks=15 masked tail; row guards only
// in the single partial block. ILP: 4 independent A dwordx4 streams + shared B.
__global__ __launch_bounds__(256) void k_gemm1_mfma(const float* __restrict__ X, const bf16x8* __restrict__ Bhi,
                                                    const bf16x8* __restrict__ Blo, float* __restrict__ out,
                                                    __bf16* __restrict__ outb, int M) {
  const int lane = threadIdx.x & 63;
  const int wid = threadIdx.x >> 6;
  const int row0 = blockIdx.x * 128 + wid * 32;  // wave: rows row0 .. row0+31
  const int kgrp = lane >> 4;
  const int rloc = lane & 15;

  f32x4 acc[2][4];
#pragma unroll
  for (int t = 0; t < 2; ++t)
#pragma unroll
    for (int nf = 0; nf < 4; ++nf) acc[t][nf] = (f32x4){0.f, 0.f, 0.f, 0.f};

  const float* xr0 = X + (size_t)(row0 + rloc) * 500;
  const float* xr1 = xr0 + 16 * 500;
  const bool full = (blockIdx.x * 128 + 128) <= M;

  if (full) {
#pragma unroll
    for (int ks = 0; ks < 15; ++ks) {
      const int k0 = ks * 32 + kgrp * 8;
      float4 p0 = *reinterpret_cast<const float4*>(xr0 + k0);
      float4 q0 = *reinterpret_cast<const float4*>(xr0 + k0 + 4);
      float4 p1 = *reinterpret_cast<const float4*>(xr1 + k0);
      float4 q1 = *reinterpret_cast<const float4*>(xr1 + k0 + 4);
      bf16x8 ah0, al0, ah1, al1;
      split8(p0, q0, ah0, al0);
      split8(p1, q1, ah1, al1);
#pragma unroll
      for (int nf = 0; nf < 4; ++nf) {
        bf16x8 bh = Bhi[(ks * 4 + nf) * 64 + lane];
        bf16x8 bl = Blo[(ks * 4 + nf) * 64 + lane];
        acc[0][nf] = __builtin_amdgcn_mfma_f32_16x16x32_bf16(ah0, bh, acc[0][nf], 0, 0, 0);
        acc[0][nf] = __builtin_amdgcn_mfma_f32_16x16x32_bf16(al0, bh, acc[0][nf], 0, 0, 0);
        acc[0][nf] = __builtin_amdgcn_mfma_f32_16x16x32_bf16(ah0, bl, acc[0][nf], 0, 0, 0);
        acc[1][nf] = __builtin_amdgcn_mfma_f32_16x16x32_bf16(ah1, bh, acc[1][nf], 0, 0, 0);
        acc[1][nf] = __builtin_amdgcn_mfma_f32_16x16x32_bf16(al1, bh, acc[1][nf], 0, 0, 0);
        acc[1][nf] = __builtin_amdgcn_mfma_f32_16x16x32_bf16(ah1, bl, acc[1][nf], 0, 0, 0);
      }
    }
    {  // ks = 15 masked tail (k = 480 + kgrp*8 + e, valid while < 500)
      const int k0 = 480 + kgrp * 8;
      float v0[8], v1[8];
#pragma unroll
      for (int e = 0; e < 8; ++e) {
        int k = k0 + e;
        bool okk = k < 500;
        v0[e] = okk ? xr0[k] : 0.f;
        v1[e] = okk ? xr1[k] : 0.f;
      }
      bf16x8 ah0, al0, ah1, al1;
#pragma unroll
      for (int e = 0; e < 8; ++e) {
        __bf16 h0 = (__bf16)v0[e];
        ah0[e] = h0; al0[e] = (__bf16)(v0[e] - (float)h0);
        __bf16 h1 = (__bf16)v1[e];
        ah1[e] = h1; al1[e] = (__bf16)(v1[e] - (float)h1);
      }
#pragma unroll
      for (int nf = 0; nf < 4; ++nf) {
        bf16x8 bh = Bhi[(15 * 4 + nf) * 64 + lane];
        bf16x8 bl = Blo[(15 * 4 + nf) * 64 + lane];
        acc[0][nf] = __builtin_amdgcn_mfma_f32_16x16x32_bf16(ah0, bh, acc[0][nf], 0, 0, 0);
        acc[0][nf] = __builtin_amdgcn_mfma_f32_16x16x32_bf16(al0, bh, acc[0][nf], 0, 0, 0);
        acc[0][nf] = __builtin_amdgcn_mfma_f32_16x16x32_bf16(ah0, bl, acc[0][nf], 0, 0, 0);
        acc[1][nf] = __builtin_amdgcn_mfma_f32_16x16x32_bf16(ah1, bh, acc[1][nf], 0, 0, 0);
        acc[1][nf] = __builtin_amdgcn_mfma_f32_16x16x32_bf16(al1, bh, acc[1][nf], 0, 0, 0);
        acc[1][nf] = __builtin_amdgcn_mfma_f32_16x16x32_bf16(ah1, bl, acc[1][nf], 0, 0, 0);
      }
    }
  } else {
    // partial block: fully guarded (runs for at most 1 block)
    const bool ok0 = row0 + rloc < M;
    const bool ok1 = row0 + 16 + rloc < M;
    for (int ks = 0; ks < 16; ++ks) {
      const int k0 = ks * 32 + kgrp * 8;
      float v0[8], v1[8];
#pragma unroll
      for (int e = 0; e < 8; ++e) {
        int k = k0 + e;
        bool okk = k < 500;
        v0[e] = (ok0 && okk) ? xr0[k] : 0.f;
        v1[e] = (ok1 && okk) ? xr1[k] : 0.f;
      }
      bf16x8 ah0, al0, ah1, al1;
#pragma unroll
      for (int e = 0; e < 8; ++e) {
        __bf16 h0 = (__bf16)v0[e];
        ah0[e] = h0; al0[e] = (__bf16)(v0[e] - (float)h0);
        __bf16 h1 = (__bf16)v1[e];
        ah1[e] = h1; al1[e] = (__bf16)(v1[e] - (float)h1);
      }
#pragma unroll
      for (int nf = 0; nf < 4; ++nf) {
        bf16x8 bh = Bhi[(ks * 4 + nf) * 64 + lane];
        bf16x8 bl = Blo[(ks * 4 + nf) * 64 + lane];
        acc[0][nf] = __builtin_amdgcn_mfma_f32_16x16x32_bf16(ah0, bh, acc[0][nf], 0, 0, 0);
        acc[0][nf] = __builtin_amdgcn_mfma_f32_16x16x32_bf16(al0, bh, acc[0][nf], 0, 0, 0);
        acc[0][nf] = __builtin_amdgcn_mfma_f32_16x16x32_bf16(ah0, bl, acc[0][nf], 0, 0, 0);
        acc[1][nf] = __builtin_amdgcn_mfma_f32_16x16x32_bf16(ah1, bh, acc[1][nf], 0, 0, 0);
        acc[1][nf] = __builtin_amdgcn_mfma_f32_16x16x32_bf16(al1, bh, acc[1][nf], 0, 0, 0);
        acc[1][nf] = __builtin_amdgcn_mfma_f32_16x16x32_bf16(ah1, bl, acc[1][nf], 0, 0, 0);
      }
    }
  }

  const int col = lane & 15;
#pragma unroll
  for (int t = 0; t < 2; ++t) {
#pragma unroll
    for (int r = 0; r < 4; ++r) {
      int rowd = row0 + t * 16 + (lane >> 4) * 4 + r;
      if (rowd >= M) continue;
#pragma unroll
      for (int nf = 0; nf < 4; ++nf) {
        float fv = acc[t][nf][r];
        out[(size_t)rowd * 64 + nf * 16 + col] = fv;
        outb[(size_t)rowd * 64 + nf * 16 + col] = (__bf16)fv;
      }
    }
  }
}

// ---------------- dense fp32 GEMM (layer 2) ----------------

__global__ __launch_bounds__(256) void k_transpose_w(const float* __restrict__ W, float* __restrict__ Wt,
                                                     int OUTC, int K, int Kpad) {
  int idx = blockIdx.x * 256 + threadIdx.x;
  int k = idx >> 6, c = idx & 63;
  if (k < Kpad) Wt[k * 64 + c] = (k < K && c < OUTC) ? W[(size_t)c * K + k] : 0.f;
}

template <bool ELU_IN>
__global__ __launch_bounds__(256) void k_gemm(const float* __restrict__ X, const float* __restrict__ Wt,
                                              const float* __restrict__ bias, float* __restrict__ out,
                                              int M, int K, int ldx, int OUTN, int ksteps) {
  __shared__ __align__(16) float xs[32][132];
  __shared__ __align__(16) float ws[32][64];
  const int t = threadIdx.x;
  const int rowg = t >> 4, colg = t & 15;
  const int brow = blockIdx.x * 128;
  float acc[8][4] = {};

  for (int ks = 0; ks < ksteps; ++ks) {
    const int k0 = ks * 32;
#pragma unroll
    for (int i = 0; i < 4; ++i) {
      int f = t + i * 256;
      int r = f >> 3, kq = f & 7;
      int grow = brow + r, gk = k0 + kq * 4;
      float4 v = {0.f, 0.f, 0.f, 0.f};
      if (grow < M && gk < K) {
        v = *reinterpret_cast<const float4*>(X + (size_t)grow * ldx + gk);
        if (ELU_IN) {
          v.x = eluf(v.x + bias[gk + 0]);
          v.y = eluf(v.y + bias[gk + 1]);
          v.z = eluf(v.z + bias[gk + 2]);
          v.w = eluf(v.w + bias[gk + 3]);
        }
      }
      xs[kq * 4 + 0][r] = v.x;
      xs[kq * 4 + 1][r] = v.y;
      xs[kq * 4 + 2][r] = v.z;
      xs[kq * 4 + 3][r] = v.w;
    }
#pragma unroll
    for (int i = 0; i < 2; ++i) {
      int f = t + i * 256;
      int kk = f >> 4, c4 = (f & 15) * 4;
      *reinterpret_cast<float4*>(&ws[kk][c4]) =
          *reinterpret_cast<const float4*>(Wt + (size_t)(k0 + kk) * 64 + c4);
    }
    __syncthreads();
#pragma unroll
    for (int k = 0; k < 32; ++k) {
      float4 xa = *reinterpret_cast<const float4*>(&xs[k][rowg * 8]);
      float4 xb = *reinterpret_cast<const float4*>(&xs[k][rowg * 8 + 4]);
      float4 wv = *reinterpret_cast<const float4*>(&ws[k][colg * 4]);
      float xr[8] = {xa.x, xa.y, xa.z, xa.w, xb.x, xb.y, xb.z, xb.w};
      float wc[4] = {wv.x, wv.y, wv.z, wv.w};
#pragma unroll
      for (int r = 0; r < 8; ++r)
#pragma unroll
        for (int c = 0; c < 4; ++c) acc[r][c] = fmaf(xr[r], wc[c], acc[r][c]);
    }
    __syncthreads();
  }

#pragma unroll
  for (int r = 0; r < 8; ++r) {
    int grow = brow + rowg * 8 + r;
    if (grow >= M) continue;
#pragma unroll
    for (int c = 0; c < 4; ++c) {
      int col = colg * 4 + c;
      if (col < OUTN) out[(size_t)grow * OUTN + col] = acc[r][c];
    }
  }
}

// alpha_s / alpha_d: per (node, head) dot of h[node, head*D..] with att vectors.
template <int D, int F>
__global__ __launch_bounds__(256) void k_alpha(const float* __restrict__ h, const float* __restrict__ a_src,
                                               const float* __restrict__ a_dst, float* __restrict__ as_,
                                               float* __restrict__ ad_, int N) {
  int idx = blockIdx.x * 256 + threadIdx.x;
  int node = idx >> 3, head = idx & 7;
  if (node >= N) return;
  const float* hr = h + (size_t)node * F + head * D;
  float ss = 0.f, sd = 0.f;
#pragma unroll
  for (int d = 0; d < D; ++d) {
    float v = hr[d];
    ss = fmaf(v, a_src[head * D + d], ss);
    sd = fmaf(v, a_dst[head * D + d], sd);
  }
  as_[idx] = ss;
  ad_[idx] = sd;
}

// One wave per dst node, two-pass softmax aggregation. HT = gathered h dtype.
template <int D, int F, typename HT>
__global__ __launch_bounds__(256) void k_agg(const HT* __restrict__ h, const float* __restrict__ as_,
                                             const float* __restrict__ ad_, const int* __restrict__ rowptr,
                                             const int* __restrict__ csr, const float* __restrict__ bias,
                                             float* __restrict__ out, int N) {
  const int lane = threadIdx.x & 63;
  const int n = blockIdx.x * 4 + (threadIdx.x >> 6);
  if (n >= N) return;
  const int r0 = rowptr[n], r1 = rowptr[n + 1];

  // ---- pass 1: per-(node,head) max & denom
  const int h1_ = lane & 7;
  const float ad_h = ad_[(size_t)n * 8 + h1_];
  float m = -1e30f, den = 0.f;
  for (int j = r0 + (lane >> 3); j < r1; j += 8) {
    int s = csr[j];
    float e = lreluf(as_[(size_t)s * 8 + h1_] + ad_h);
    float nm = fmaxf(m, e);
    den = den * __expf(m - nm) + __expf(e - nm);
    m = nm;
  }
#pragma unroll
  for (int off = 8; off < 64; off <<= 1) {
    float mo = __shfl_xor(m, off);
    float dn = __shfl_xor(den, off);
    float nm = fmaxf(m, mo);
    den = den * __expf(m - nm) + dn * __expf(mo - nm);
    m = nm;
  }

  // ---- pass 2: lane = output feature
  const int head = (lane < F) ? (lane / D) : 0;
  const int fidx = (lane < F) ? lane : 0;
  const float m_h = __shfl(m, head);
  const float inv_den = 1.f / __shfl(den, head);
  const float ad_n = __shfl(ad_h, head);

  float acc0 = 0.f, acc1 = 0.f, acc2 = 0.f, acc3 = 0.f;
  int j = r0;
  for (; j + 3 < r1; j += 4) {
    int s0 = csr[j + 0], s1 = csr[j + 1], s2 = csr[j + 2], s3 = csr[j + 3];
    float a0 = as_[(size_t)s0 * 8 + head];
    float a1 = as_[(size_t)s1 * 8 + head];
    float a2 = as_[(size_t)s2 * 8 + head];
    float a3 = as_[(size_t)s3 * 8 + head];
    float v0 = (float)h[(size_t)s0 * F + fidx];
    float v1 = (float)h[(size_t)s1 * F + fidx];
    float v2 = (float)h[(size_t)s2 * F + fidx];
    float v3 = (float)h[(size_t)s3 * F + fidx];
    acc0 = fmaf(__expf(lreluf(a0 + ad_n) - m_h), v0, acc0);
    acc1 = fmaf(__expf(lreluf(a1 + ad_n) - m_h), v1, acc1);
    acc2 = fmaf(__expf(lreluf(a2 + ad_n) - m_h), v2, acc2);
    acc3 = fmaf(__expf(lreluf(a3 + ad_n) - m_h), v3, acc3);
  }
  for (; j < r1; ++j) {
    int s = csr[j];
    float a = as_[(size_t)s * 8 + head];
    float v = (float)h[(size_t)s * F + fidx];
    acc0 = fmaf(__expf(lreluf(a + ad_n) - m_h), v, acc0);
  }
  if (lane < F)
    out[(size_t)n * F + lane] = (acc0 + acc1 + acc2 + acc3) * inv_den + (bias ? bias[lane] : 0.f);
}

// ---------------- launch ----------------

extern "C" void kernel_launch(void* const* d_in, const int* in_sizes, int n_in,
                              void* d_out, int out_size, void* d_ws, size_t ws_size,
                              hipStream_t stream) {
  const float* x    = (const float*)d_in[0];
  const int*   ei   = (const int*)d_in[1];
  const float* W1   = (const float*)d_in[2];
  const float* at_s1 = (const float*)d_in[3];
  const float* at_d1 = (const float*)d_in[4];
  const float* b1   = (const float*)d_in[5];
  const float* W2   = (const float*)d_in[6];
  const float* at_s2 = (const float*)d_in[7];
  const float* at_d2 = (const float*)d_in[8];
  const float* b2   = (const float*)d_in[9];
  float* out = (float*)d_out;

  const int N = in_sizes[0] / 500;
  const int E = in_sizes[1] / 2;

  char* w = (char*)d_ws;
  auto alloc = [&](size_t bytes) -> void* {
    void* p = (void*)w;
    w += (bytes + 255) & ~(size_t)255;
    return p;
  };
  int*   rowptr = (int*)alloc((size_t)(N + 1) * 4);
  int*   cursor = (int*)alloc((size_t)N * 4);
  int*   deg    = (int*)alloc((size_t)N * 4);
  int*   flag   = (int*)alloc(256);
  int*   bsum   = (int*)alloc(4096);
  int*   boff   = (int*)alloc(4096);
  int*   ei_c   = (int*)alloc((size_t)2 * E * 4);
  int*   csr    = (int*)alloc((size_t)(E + N) * 4);
  float* h1     = (float*)alloc((size_t)N * 64 * 4);
  float* o1     = (float*)alloc((size_t)N * 64 * 4);
  float* asb    = (float*)alloc((size_t)N * 8 * 4);
  float* adb    = (float*)alloc((size_t)N * 8 * 4);
  float* Wt2    = (float*)alloc((size_t)64 * 64 * 4);
  __bf16* Bhi1  = (__bf16*)alloc((size_t)32768 * 2);
  __bf16* Blo1  = (__bf16*)alloc((size_t)32768 * 2);
  __bf16* h1b   = (__bf16*)alloc((size_t)N * 64 * 2);

  auto cdiv = [](int a, int b) { return (a + b - 1) / b; };
  const int nbN = cdiv(N, 256);

  // CSR build (shared by both layers: same graph + self-loops)
  k_init<<<nbN, 256, 0, stream>>>(deg, flag, N);
  k_detect<<<cdiv(50000, 256), 256, 0, stream>>>(ei, flag, 50000);
  k_convert<<<cdiv(2 * E, 256), 256, 0, stream>>>(ei, flag, ei_c, 2 * E);
  k_count<<<cdiv(E, 256), 256, 0, stream>>>(ei_c, deg, E);
  k_blocksum<<<nbN, 256, 0, stream>>>(deg, bsum, N);
  k_scan_bsum<<<1, 512, 0, stream>>>(bsum, boff, nbN, rowptr, N);
  k_scan_final<<<nbN, 256, 0, stream>>>(deg, boff, rowptr, cursor, N);
  {
    const int G = 768;
    k_fill_shard<<<8 * G, 256, 0, stream>>>(ei_c, cursor, csr, E, N, cdiv(E + N, G));
  }

  // Layer 1 (split-bf16 MFMA GEMM; also emits bf16 h for the gather)
  k_prep_b1<<<cdiv(32768, 256), 256, 0, stream>>>(W1, Bhi1, Blo1);
  k_gemm1_mfma<<<cdiv(N, 128), 256, 0, stream>>>(x, (const bf16x8*)Bhi1, (const bf16x8*)Blo1, h1, h1b, N);
  k_alpha<8, 64><<<cdiv(N * 8, 256), 256, 0, stream>>>(h1, at_s1, at_d1, asb, adb, N);
  k_agg<8, 64, __bf16><<<cdiv(N, 4), 256, 0, stream>>>(h1b, asb, adb, rowptr, csr, nullptr, o1, N);

  // Layer 2 (bias b1 + ELU fused into GEMM2 input load)
  k_transpose_w<<<cdiv(64 * 64, 256), 256, 0, stream>>>(W2, Wt2, 56, 64, 64);
  k_gemm<true><<<cdiv(N, 128), 256, 0, stream>>>(o1, Wt2, b1, h1, N, 64, 64, 56, 2);
  k_alpha<7, 56><<<cdiv(N * 8, 256), 256, 0, stream>>>(h1, at_s2, at_d2, asb, adb, N);
  k_agg<7, 56, float><<<cdiv(N, 4), 256, 0, stream>>>(h1, asb, adb, rowptr, csr, b2, out, N);
}

// Round 6
// 501.819 us; speedup vs baseline: 1.0297x; 1.0297x over previous
//
#include <hip/hip_runtime.h>

#define NEG_SLOPE 0.2f

typedef __bf16 bf16x8 __attribute__((ext_vector_type(8)));
typedef float f32x4 __attribute__((ext_vector_type(4)));

__device__ __forceinline__ float eluf(float x) { return x > 0.f ? x : __expf(x) - 1.f; }
__device__ __forceinline__ float lreluf(float x) { return x > 0.f ? x : NEG_SLOPE * x; }

__device__ __forceinline__ void split8(const float4& p, const float4& q, bf16x8& hi, bf16x8& lo) {
  float v[8] = {p.x, p.y, p.z, p.w, q.x, q.y, q.z, q.w};
#pragma unroll
  for (int e = 0; e < 8; ++e) {
    __bf16 h = (__bf16)v[e];
    hi[e] = h;
    lo[e] = (__bf16)(v[e] - (float)h);
  }
}

// ---------------- CSR build ----------------

__global__ __launch_bounds__(256) void k_init(int* __restrict__ deg, int* __restrict__ flag, int N) {
  int i = blockIdx.x * 256 + threadIdx.x;
  if (i < N) deg[i] = 1;  // self-loop
  if (i == 0) *flag = 0;
}

// If edge_index arrived as int64, every odd int32 word is 0 (values < 2^31).
__global__ __launch_bounds__(256) void k_detect(const int* __restrict__ raw, int* __restrict__ flag, int nCheck) {
  int i = blockIdx.x * 256 + threadIdx.x;
  if (i < nCheck && raw[2 * i + 1] != 0) atomicOr(flag, 1);
}

__global__ __launch_bounds__(256) void k_convert(const int* __restrict__ raw, const int* __restrict__ flag,
                                                 int* __restrict__ out, int n) {
  int i = blockIdx.x * 256 + threadIdx.x;
  if (i >= n) return;
  bool is32 = (*flag != 0);
  out[i] = is32 ? raw[i] : raw[2 * i];
}

__global__ __launch_bounds__(256) void k_count(const int* __restrict__ ei, int* __restrict__ deg, int E) {
  int e = blockIdx.x * 256 + threadIdx.x;
  if (e < E) atomicAdd(&deg[ei[E + e]], 1);
}

__global__ __launch_bounds__(256) void k_blocksum(const int* __restrict__ deg, int* __restrict__ bsum, int N) {
  __shared__ int s[256];
  int t = threadIdx.x;
  int i = blockIdx.x * 256 + t;
  s[t] = (i < N) ? deg[i] : 0;
  __syncthreads();
  for (int off = 128; off > 0; off >>= 1) {
    if (t < off) s[t] += s[t + off];
    __syncthreads();
  }
  if (t == 0) bsum[blockIdx.x] = s[0];
}

__global__ __launch_bounds__(512) void k_scan_bsum(const int* __restrict__ bsum, int* __restrict__ boff,
                                                   int nb, int* __restrict__ rowptr, int N) {
  __shared__ int s[512];
  int t = threadIdx.x;
  int v = (t < nb) ? bsum[t] : 0;
  s[t] = v;
  __syncthreads();
  for (int off = 1; off < 512; off <<= 1) {
    int u = (t >= off) ? s[t - off] : 0;
    __syncthreads();
    s[t] += u;
    __syncthreads();
  }
  if (t < nb) boff[t] = s[t] - v;       // exclusive
  if (t == nb - 1) rowptr[N] = s[t];    // total = E + N
}

__global__ __launch_bounds__(256) void k_scan_final(const int* __restrict__ deg, const int* __restrict__ boff,
                                                    int* __restrict__ rowptr, int* __restrict__ cursor, int N) {
  __shared__ int s[256];
  int t = threadIdx.x;
  int i = blockIdx.x * 256 + t;
  int v = (i < N) ? deg[i] : 0;
  s[t] = v;
  __syncthreads();
  for (int off = 1; off < 256; off <<= 1) {
    int u = (t >= off) ? s[t - off] : 0;
    __syncthreads();
    s[t] += u;
    __syncthreads();
  }
  if (i < N) {
    int ex = boff[blockIdx.x] + s[t] - v;
    rowptr[i] = ex;
    cursor[i] = ex;
  }
}

// XCD-sharded CSR fill (see R3): each XCD's csr writes stay in its own L2.
__global__ __launch_bounds__(256) void k_fill_shard(const int* __restrict__ ei, int* __restrict__ cursor,
                                                    int* __restrict__ csr, int E, int N, int CH) {
  const int shard = blockIdx.x & 7;
  const int chunk = blockIdx.x >> 3;
  const int i0 = chunk * CH;
  const int i1 = min(i0 + CH, E + N);
  for (int idx = i0 + (int)threadIdx.x; idx < i1; idx += 256) {
    int d = (idx < E) ? ei[E + idx] : idx - E;
    if (((d >> 13) & 7) != shard) continue;
    int s = (idx < E) ? ei[idx] : idx - E;
    int pos = atomicAdd(&cursor[d], 1);
    csr[pos] = s;
  }
}

// ---------------- layer-1 GEMM: split-bf16 MFMA, LDS-staged X ----------------

// Pack W1^T into per-lane MFMA B fragments (hi/lo split).
__global__ __launch_bounds__(256) void k_prep_b1(const float* __restrict__ W1, __bf16* __restrict__ bhi,
                                                 __bf16* __restrict__ blo) {
  int idx = blockIdx.x * 256 + threadIdx.x;  // 0 .. 16*4*64*8-1 = 32767
  if (idx >= 16 * 4 * 64 * 8) return;
  int e = idx & 7;
  int lane = (idx >> 3) & 63;
  int nf = (idx >> 9) & 3;
  int ks = idx >> 11;
  int k = ks * 32 + (lane >> 4) * 8 + e;
  int col = nf * 16 + (lane & 15);
  float w = (k < 500) ? W1[(size_t)col * 500 + k] : 0.f;
  __bf16 h = (__bf16)w;
  bhi[idx] = h;
  blo[idx] = (__bf16)(w - (float)h);
}

// C[M x 64] = X[M x 500] * W1^T via 3-term split-bf16 MFMA; emits fp32 + bf16 C.
// 64-row tile, 4 waves x 16 rows. X staged global->LDS via global_load_lds
// (width 16), double-buffered, XOR-swizzled (byte ^= (row&7)<<4) applied on
// the SOURCE address (linear LDS dest) and on the ds_read side (rule #21).
// In-flight staging lives in LDS, not VGPRs -> MLP no longer register-capped.
__global__ __launch_bounds__(256) void k_gemm1_lds(const float* __restrict__ X, const bf16x8* __restrict__ Bhi,
                                                   const bf16x8* __restrict__ Blo, float* __restrict__ out,
                                                   __bf16* __restrict__ outb, int M) {
  __shared__ __align__(16) float xs[2][2048];  // 2 x [64 rows][32 k] fp32, swizzled, 8KB each
  const int lane = threadIdx.x & 63;
  const int wid = threadIdx.x >> 6;
  const int row0 = blockIdx.x * 64;
  const int kgrp = lane >> 4;
  const int rloc = lane & 15;
  const int myrow = wid * 16 + rloc;

  // Swizzled ds_read float offsets (constant across iterations).
  const int ub = myrow * 128 + kgrp * 32;                 // unswizzled byte base
  const int sw1 = (ub ^ ((myrow & 7) << 4)) >> 2;         // first 16B
  const int sw2 = ((ub + 16) ^ ((myrow & 7) << 4)) >> 2;  // second 16B

  // Staging: 8 x 1KB insts per block (2 per wave). Linear dest byte s maps to
  // row r = s>>7, source k-bytes kb = (s&127) ^ ((r&7)<<4)  (swizzle inverse).
  int st_r[2], st_kf[2];
#pragma unroll
  for (int j = 0; j < 2; ++j) {
    int s = (wid * 2 + j) * 1024 + lane * 16;
    int r = s >> 7;
    int kb = (s & 127) ^ ((r & 7) << 4);
    st_r[j] = min(row0 + r, M - 1);  // clamp: over-read safe, C-write guarded
    st_kf[j] = kb >> 2;
  }

  auto stage = [&](int buf, int ks) {
#pragma unroll
    for (int j = 0; j < 2; ++j) {
      const float* src = X + (size_t)st_r[j] * 500 + ks * 32 + st_kf[j];
      __builtin_amdgcn_global_load_lds(
          (const __attribute__((address_space(1))) void*)src,
          (__attribute__((address_space(3))) void*)&xs[buf][(wid * 2 + j) * 256], 16, 0, 0);
    }
  };

  f32x4 acc[4];
#pragma unroll
  for (int nf = 0; nf < 4; ++nf) acc[nf] = (f32x4){0.f, 0.f, 0.f, 0.f};

  stage(0, 0);
  __syncthreads();

  int cur = 0;
  for (int ks = 0; ks < 15; ++ks) {
    if (ks < 14) stage(cur ^ 1, ks + 1);  // issue next tile early (async)
    float4 p = *reinterpret_cast<const float4*>(&xs[cur][sw1]);
    float4 q = *reinterpret_cast<const float4*>(&xs[cur][sw2]);
    bf16x8 ah, al;
    split8(p, q, ah, al);
#pragma unroll
    for (int nf = 0; nf < 4; ++nf) {
      bf16x8 bh = Bhi[(ks * 4 + nf) * 64 + lane];
      bf16x8 bl = Blo[(ks * 4 + nf) * 64 + lane];
      acc[nf] = __builtin_amdgcn_mfma_f32_16x16x32_bf16(ah, bh, acc[nf], 0, 0, 0);
      acc[nf] = __builtin_amdgcn_mfma_f32_16x16x32_bf16(al, bh, acc[nf], 0, 0, 0);
      acc[nf] = __builtin_amdgcn_mfma_f32_16x16x32_bf16(ah, bl, acc[nf], 0, 0, 0);
    }
    __syncthreads();  // drains lgkm + vmcnt: next buffer ready, cur reads done
    cur ^= 1;
  }

  {  // ks = 15 tail (k = 480..499) from guarded register loads
    const bool rowok = row0 + myrow < M;
    const float* xrow = X + (size_t)(row0 + myrow) * 500;
    float v[8];
#pragma unroll
    for (int e = 0; e < 8; ++e) {
      int k = 480 + kgrp * 8 + e;
      v[e] = (rowok && k < 500) ? xrow[k] : 0.f;
    }
    bf16x8 ah, al;
#pragma unroll
    for (int e = 0; e < 8; ++e) {
      __bf16 h = (__bf16)v[e];
      ah[e] = h;
      al[e] = (__bf16)(v[e] - (float)h);
    }
#pragma unroll
    for (int nf = 0; nf < 4; ++nf) {
      bf16x8 bh = Bhi[(15 * 4 + nf) * 64 + lane];
      bf16x8 bl = Blo[(15 * 4 + nf) * 64 + lane];
      acc[nf] = __builtin_amdgcn_mfma_f32_16x16x32_bf16(ah, bh, acc[nf], 0, 0, 0);
      acc[nf] = __builtin_amdgcn_mfma_f32_16x16x32_bf16(al, bh, acc[nf], 0, 0, 0);
      acc[nf] = __builtin_amdgcn_mfma_f32_16x16x32_bf16(ah, bl, acc[nf], 0, 0, 0);
    }
  }

  const int colw = lane & 15;
#pragma unroll
  for (int r = 0; r < 4; ++r) {
    int rowd = row0 + wid * 16 + (lane >> 4) * 4 + r;
    if (rowd >= M) continue;
#pragma unroll
    for (int nf = 0; nf < 4; ++nf) {
      float fv = acc[nf][r];
      out[(size_t)rowd * 64 + nf * 16 + colw] = fv;
      outb[(size_t)rowd * 64 + nf * 16 + colw] = (__bf16)fv;
    }
  }
}

// ---------------- dense fp32 GEMM (layer 2) ----------------

__global__ __launch_bounds__(256) void k_transpose_w(const float* __restrict__ W, float* __restrict__ Wt,
                                                     int OUTC, int K, int Kpad) {
  int idx = blockIdx.x * 256 + threadIdx.x;
  int k = idx >> 6, c = idx & 63;
  if (k < Kpad) Wt[k * 64 + c] = (k < K && c < OUTC) ? W[(size_t)c * K + k] : 0.f;
}

template <bool ELU_IN>
__global__ __launch_bounds__(256) void k_gemm(const float* __restrict__ X, const float* __restrict__ Wt,
                                              const float* __restrict__ bias, float* __restrict__ out,
                                              int M, int K, int ldx, int OUTN, int ksteps) {
  __shared__ __align__(16) float xs[32][132];
  __shared__ __align__(16) float ws[32][64];
  const int t = threadIdx.x;
  const int rowg = t >> 4, colg = t & 15;
  const int brow = blockIdx.x * 128;
  float acc[8][4] = {};

  for (int ks = 0; ks < ksteps; ++ks) {
    const int k0 = ks * 32;
#pragma unroll
    for (int i = 0; i < 4; ++i) {
      int f = t + i * 256;
      int r = f >> 3, kq = f & 7;
      int grow = brow + r, gk = k0 + kq * 4;
      float4 v = {0.f, 0.f, 0.f, 0.f};
      if (grow < M && gk < K) {
        v = *reinterpret_cast<const float4*>(X + (size_t)grow * ldx + gk);
        if (ELU_IN) {
          v.x = eluf(v.x + bias[gk + 0]);
          v.y = eluf(v.y + bias[gk + 1]);
          v.z = eluf(v.z + bias[gk + 2]);
          v.w = eluf(v.w + bias[gk + 3]);
        }
      }
      xs[kq * 4 + 0][r] = v.x;
      xs[kq * 4 + 1][r] = v.y;
      xs[kq * 4 + 2][r] = v.z;
      xs[kq * 4 + 3][r] = v.w;
    }
#pragma unroll
    for (int i = 0; i < 2; ++i) {
      int f = t + i * 256;
      int kk = f >> 4, c4 = (f & 15) * 4;
      *reinterpret_cast<float4*>(&ws[kk][c4]) =
          *reinterpret_cast<const float4*>(Wt + (size_t)(k0 + kk) * 64 + c4);
    }
    __syncthreads();
#pragma unroll
    for (int k = 0; k < 32; ++k) {
      float4 xa = *reinterpret_cast<const float4*>(&xs[k][rowg * 8]);
      float4 xb = *reinterpret_cast<const float4*>(&xs[k][rowg * 8 + 4]);
      float4 wv = *reinterpret_cast<const float4*>(&ws[k][colg * 4]);
      float xr[8] = {xa.x, xa.y, xa.z, xa.w, xb.x, xb.y, xb.z, xb.w};
      float wc[4] = {wv.x, wv.y, wv.z, wv.w};
#pragma unroll
      for (int r = 0; r < 8; ++r)
#pragma unroll
        for (int c = 0; c < 4; ++c) acc[r][c] = fmaf(xr[r], wc[c], acc[r][c]);
    }
    __syncthreads();
  }

#pragma unroll
  for (int r = 0; r < 8; ++r) {
    int grow = brow + rowg * 8 + r;
    if (grow >= M) continue;
#pragma unroll
    for (int c = 0; c < 4; ++c) {
      int col = colg * 4 + c;
      if (col < OUTN) out[(size_t)grow * OUTN + col] = acc[r][c];
    }
  }
}

// alpha_s / alpha_d: per (node, head) dot of h[node, head*D..] with att vectors.
template <int D, int F>
__global__ __launch_bounds__(256) void k_alpha(const float* __restrict__ h, const float* __restrict__ a_src,
                                               const float* __restrict__ a_dst, float* __restrict__ as_,
                                               float* __restrict__ ad_, int N) {
  int idx = blockIdx.x * 256 + threadIdx.x;
  int node = idx >> 3, head = idx & 7;
  if (node >= N) return;
  const float* hr = h + (size_t)node * F + head * D;
  float ss = 0.f, sd = 0.f;
#pragma unroll
  for (int d = 0; d < D; ++d) {
    float v = hr[d];
    ss = fmaf(v, a_src[head * D + d], ss);
    sd = fmaf(v, a_dst[head * D + d], sd);
  }
  as_[idx] = ss;
  ad_[idx] = sd;
}

// One wave per dst node, two-pass softmax aggregation. HT = gathered h dtype.
template <int D, int F, typename HT>
__global__ __launch_bounds__(256) void k_agg(const HT* __restrict__ h, const float* __restrict__ as_,
                                             const float* __restrict__ ad_, const int* __restrict__ rowptr,
                                             const int* __restrict__ csr, const float* __restrict__ bias,
                                             float* __restrict__ out, int N) {
  const int lane = threadIdx.x & 63;
  const int n = blockIdx.x * 4 + (threadIdx.x >> 6);
  if (n >= N) return;
  const int r0 = rowptr[n], r1 = rowptr[n + 1];

  // ---- pass 1: per-(node,head) max & denom
  const int h1_ = lane & 7;
  const float ad_h = ad_[(size_t)n * 8 + h1_];
  float m = -1e30f, den = 0.f;
  for (int j = r0 + (lane >> 3); j < r1; j += 8) {
    int s = csr[j];
    float e = lreluf(as_[(size_t)s * 8 + h1_] + ad_h);
    float nm = fmaxf(m, e);
    den = den * __expf(m - nm) + __expf(e - nm);
    m = nm;
  }
#pragma unroll
  for (int off = 8; off < 64; off <<= 1) {
    float mo = __shfl_xor(m, off);
    float dn = __shfl_xor(den, off);
    float nm = fmaxf(m, mo);
    den = den * __expf(m - nm) + dn * __expf(mo - nm);
    m = nm;
  }

  // ---- pass 2: lane = output feature
  const int head = (lane < F) ? (lane / D) : 0;
  const int fidx = (lane < F) ? lane : 0;
  const float m_h = __shfl(m, head);
  const float inv_den = 1.f / __shfl(den, head);
  const float ad_n = __shfl(ad_h, head);

  float acc0 = 0.f, acc1 = 0.f, acc2 = 0.f, acc3 = 0.f;
  int j = r0;
  for (; j + 3 < r1; j += 4) {
    int s0 = csr[j + 0], s1 = csr[j + 1], s2 = csr[j + 2], s3 = csr[j + 3];
    float a0 = as_[(size_t)s0 * 8 + head];
    float a1 = as_[(size_t)s1 * 8 + head];
    float a2 = as_[(size_t)s2 * 8 + head];
    float a3 = as_[(size_t)s3 * 8 + head];
    float v0 = (float)h[(size_t)s0 * F + fidx];
    float v1 = (float)h[(size_t)s1 * F + fidx];
    float v2 = (float)h[(size_t)s2 * F + fidx];
    float v3 = (float)h[(size_t)s3 * F + fidx];
    acc0 = fmaf(__expf(lreluf(a0 + ad_n) - m_h), v0, acc0);
    acc1 = fmaf(__expf(lreluf(a1 + ad_n) - m_h), v1, acc1);
    acc2 = fmaf(__expf(lreluf(a2 + ad_n) - m_h), v2, acc2);
    acc3 = fmaf(__expf(lreluf(a3 + ad_n) - m_h), v3, acc3);
  }
  for (; j < r1; ++j) {
    int s = csr[j];
    float a = as_[(size_t)s * 8 + head];
    float v = (float)h[(size_t)s * F + fidx];
    acc0 = fmaf(__expf(lreluf(a + ad_n) - m_h), v, acc0);
  }
  if (lane < F)
    out[(size_t)n * F + lane] = (acc0 + acc1 + acc2 + acc3) * inv_den + (bias ? bias[lane] : 0.f);
}

// ---------------- launch ----------------

extern "C" void kernel_launch(void* const* d_in, const int* in_sizes, int n_in,
                              void* d_out, int out_size, void* d_ws, size_t ws_size,
                              hipStream_t stream) {
  const float* x    = (const float*)d_in[0];
  const int*   ei   = (const int*)d_in[1];
  const float* W1   = (const float*)d_in[2];
  const float* at_s1 = (const float*)d_in[3];
  const float* at_d1 = (const float*)d_in[4];
  const float* b1   = (const float*)d_in[5];
  const float* W2   = (const float*)d_in[6];
  const float* at_s2 = (const float*)d_in[7];
  const float* at_d2 = (const float*)d_in[8];
  const float* b2   = (const float*)d_in[9];
  float* out = (float*)d_out;

  const int N = in_sizes[0] / 500;
  const int E = in_sizes[1] / 2;

  char* w = (char*)d_ws;
  auto alloc = [&](size_t bytes) -> void* {
    void* p = (void*)w;
    w += (bytes + 255) & ~(size_t)255;
    return p;
  };
  int*   rowptr = (int*)alloc((size_t)(N + 1) * 4);
  int*   cursor = (int*)alloc((size_t)N * 4);
  int*   deg    = (int*)alloc((size_t)N * 4);
  int*   flag   = (int*)alloc(256);
  int*   bsum   = (int*)alloc(4096);
  int*   boff   = (int*)alloc(4096);
  int*   ei_c   = (int*)alloc((size_t)2 * E * 4);
  int*   csr    = (int*)alloc((size_t)(E + N) * 4);
  float* h1     = (float*)alloc((size_t)N * 64 * 4);
  float* o1     = (float*)alloc((size_t)N * 64 * 4);
  float* asb    = (float*)alloc((size_t)N * 8 * 4);
  float* adb    = (float*)alloc((size_t)N * 8 * 4);
  float* Wt2    = (float*)alloc((size_t)64 * 64 * 4);
  __bf16* Bhi1  = (__bf16*)alloc((size_t)32768 * 2);
  __bf16* Blo1  = (__bf16*)alloc((size_t)32768 * 2);
  __bf16* h1b   = (__bf16*)alloc((size_t)N * 64 * 2);

  auto cdiv = [](int a, int b) { return (a + b - 1) / b; };
  const int nbN = cdiv(N, 256);

  // CSR build (shared by both layers: same graph + self-loops)
  k_init<<<nbN, 256, 0, stream>>>(deg, flag, N);
  k_detect<<<cdiv(50000, 256), 256, 0, stream>>>(ei, flag, 50000);
  k_convert<<<cdiv(2 * E, 256), 256, 0, stream>>>(ei, flag, ei_c, 2 * E);
  k_count<<<cdiv(E, 256), 256, 0, stream>>>(ei_c, deg, E);
  k_blocksum<<<nbN, 256, 0, stream>>>(deg, bsum, N);
  k_scan_bsum<<<1, 512, 0, stream>>>(bsum, boff, nbN, rowptr, N);
  k_scan_final<<<nbN, 256, 0, stream>>>(deg, boff, rowptr, cursor, N);
  {
    const int G = 768;
    k_fill_shard<<<8 * G, 256, 0, stream>>>(ei_c, cursor, csr, E, N, cdiv(E + N, G));
  }

  // Layer 1 (split-bf16 MFMA GEMM, LDS-staged; also emits bf16 h for the gather)
  k_prep_b1<<<cdiv(32768, 256), 256, 0, stream>>>(W1, Bhi1, Blo1);
  k_gemm1_lds<<<cdiv(N, 64), 256, 0, stream>>>(x, (const bf16x8*)Bhi1, (const bf16x8*)Blo1, h1, h1b, N);
  k_alpha<8, 64><<<cdiv(N * 8, 256), 256, 0, stream>>>(h1, at_s1, at_d1, asb, adb, N);
  k_agg<8, 64, __bf16><<<cdiv(N, 4), 256, 0, stream>>>(h1b, asb, adb, rowptr, csr, nullptr, o1, N);

  // Layer 2 (bias b1 + ELU fused into GEMM2 input load)
  k_transpose_w<<<cdiv(64 * 64, 256), 256, 0, stream>>>(W2, Wt2, 56, 64, 64);
  k_gemm<true><<<cdiv(N, 128), 256, 0, stream>>>(o1, Wt2, b1, h1, N, 64, 64, 56, 2);
  k_alpha<7, 56><<<cdiv(N * 8, 256), 256, 0, stream>>>(h1, at_s2, at_d2, asb, adb, N);
  k_agg<7, 56, float><<<cdiv(N, 4), 256, 0, stream>>>(h1, asb, adb, rowptr, csr, b2, out, N);
}

// Round 7
// 464.064 us; speedup vs baseline: 1.1134x; 1.0814x over previous
//
#include <hip/hip_runtime.h>

#define NEG_SLOPE 0.2f

typedef __bf16 bf16x8 __attribute__((ext_vector_type(8)));
typedef float f32x4 __attribute__((ext_vector_type(4)));

__device__ __forceinline__ float eluf(float x) { return x > 0.f ? x : __expf(x) - 1.f; }
__device__ __forceinline__ float lreluf(float x) { return x > 0.f ? x : NEG_SLOPE * x; }
__device__ __forceinline__ float bflo(unsigned u) { return __uint_as_float(u << 16); }
__device__ __forceinline__ float bfhi(unsigned u) { return __uint_as_float(u & 0xffff0000u); }

__device__ __forceinline__ void split8(const float4& p, const float4& q, bf16x8& hi, bf16x8& lo) {
  float v[8] = {p.x, p.y, p.z, p.w, q.x, q.y, q.z, q.w};
#pragma unroll
  for (int e = 0; e < 8; ++e) {
    __bf16 h = (__bf16)v[e];
    hi[e] = h;
    lo[e] = (__bf16)(v[e] - (float)h);
  }
}

// ---------------- CSR build ----------------

__global__ __launch_bounds__(256) void k_init(int* __restrict__ deg, int* __restrict__ flag, int N) {
  int i = blockIdx.x * 256 + threadIdx.x;
  if (i < N) deg[i] = 1;  // self-loop
  if (i == 0) *flag = 0;
}

// If edge_index arrived as int64, every odd int32 word is 0 (values < 2^31).
__global__ __launch_bounds__(256) void k_detect(const int* __restrict__ raw, int* __restrict__ flag, int nCheck) {
  int i = blockIdx.x * 256 + threadIdx.x;
  if (i < nCheck && raw[2 * i + 1] != 0) atomicOr(flag, 1);
}

__global__ __launch_bounds__(256) void k_convert(const int* __restrict__ raw, const int* __restrict__ flag,
                                                 int* __restrict__ out, int n) {
  int i = blockIdx.x * 256 + threadIdx.x;
  if (i >= n) return;
  bool is32 = (*flag != 0);
  out[i] = is32 ? raw[i] : raw[2 * i];
}

__global__ __launch_bounds__(256) void k_count(const int* __restrict__ ei, int* __restrict__ deg, int E) {
  int e = blockIdx.x * 256 + threadIdx.x;
  if (e < E) atomicAdd(&deg[ei[E + e]], 1);
}

__global__ __launch_bounds__(256) void k_blocksum(const int* __restrict__ deg, int* __restrict__ bsum, int N) {
  __shared__ int s[256];
  int t = threadIdx.x;
  int i = blockIdx.x * 256 + t;
  s[t] = (i < N) ? deg[i] : 0;
  __syncthreads();
  for (int off = 128; off > 0; off >>= 1) {
    if (t < off) s[t] += s[t + off];
    __syncthreads();
  }
  if (t == 0) bsum[blockIdx.x] = s[0];
}

__global__ __launch_bounds__(512) void k_scan_bsum(const int* __restrict__ bsum, int* __restrict__ boff,
                                                   int nb, int* __restrict__ rowptr, int N) {
  __shared__ int s[512];
  int t = threadIdx.x;
  int v = (t < nb) ? bsum[t] : 0;
  s[t] = v;
  __syncthreads();
  for (int off = 1; off < 512; off <<= 1) {
    int u = (t >= off) ? s[t - off] : 0;
    __syncthreads();
    s[t] += u;
    __syncthreads();
  }
  if (t < nb) boff[t] = s[t] - v;       // exclusive
  if (t == nb - 1) rowptr[N] = s[t];    // total = E + N
}

__global__ __launch_bounds__(256) void k_scan_final(const int* __restrict__ deg, const int* __restrict__ boff,
                                                    int* __restrict__ rowptr, int* __restrict__ cursor, int N) {
  __shared__ int s[256];
  int t = threadIdx.x;
  int i = blockIdx.x * 256 + t;
  int v = (i < N) ? deg[i] : 0;
  s[t] = v;
  __syncthreads();
  for (int off = 1; off < 256; off <<= 1) {
    int u = (t >= off) ? s[t - off] : 0;
    __syncthreads();
    s[t] += u;
    __syncthreads();
  }
  if (i < N) {
    int ex = boff[blockIdx.x] + s[t] - v;
    rowptr[i] = ex;
    cursor[i] = ex;
  }
}

// XCD-sharded CSR fill (see R3): each XCD's csr writes stay in its own L2.
__global__ __launch_bounds__(256) void k_fill_shard(const int* __restrict__ ei, int* __restrict__ cursor,
                                                    int* __restrict__ csr, int E, int N, int CH) {
  const int shard = blockIdx.x & 7;
  const int chunk = blockIdx.x >> 3;
  const int i0 = chunk * CH;
  const int i1 = min(i0 + CH, E + N);
  for (int idx = i0 + (int)threadIdx.x; idx < i1; idx += 256) {
    int d = (idx < E) ? ei[E + idx] : idx - E;
    if (((d >> 13) & 7) != shard) continue;
    int s = (idx < E) ? ei[idx] : idx - E;
    int pos = atomicAdd(&cursor[d], 1);
    csr[pos] = s;
  }
}

// ---------------- layer-1 GEMM: split-bf16 MFMA, LDS-staged X ----------------

__global__ __launch_bounds__(256) void k_prep_b1(const float* __restrict__ W1, __bf16* __restrict__ bhi,
                                                 __bf16* __restrict__ blo) {
  int idx = blockIdx.x * 256 + threadIdx.x;  // 0 .. 16*4*64*8-1 = 32767
  if (idx >= 16 * 4 * 64 * 8) return;
  int e = idx & 7;
  int lane = (idx >> 3) & 63;
  int nf = (idx >> 9) & 3;
  int ks = idx >> 11;
  int k = ks * 32 + (lane >> 4) * 8 + e;
  int col = nf * 16 + (lane & 15);
  float w = (k < 500) ? W1[(size_t)col * 500 + k] : 0.f;
  __bf16 h = (__bf16)w;
  bhi[idx] = h;
  blo[idx] = (__bf16)(w - (float)h);
}

// C[M x 64] = X[M x 500] * W1^T via 3-term split-bf16 MFMA; emits fp32 + bf16 C.
// 64-row tile, 4 waves x 16 rows, global_load_lds dbuf with XOR swizzle.
__global__ __launch_bounds__(256) void k_gemm1_lds(const float* __restrict__ X, const bf16x8* __restrict__ Bhi,
                                                   const bf16x8* __restrict__ Blo, float* __restrict__ out,
                                                   __bf16* __restrict__ outb, int M) {
  __shared__ __align__(16) float xs[2][2048];
  const int lane = threadIdx.x & 63;
  const int wid = threadIdx.x >> 6;
  const int row0 = blockIdx.x * 64;
  const int kgrp = lane >> 4;
  const int rloc = lane & 15;
  const int myrow = wid * 16 + rloc;

  const int ub = myrow * 128 + kgrp * 32;
  const int sw1 = (ub ^ ((myrow & 7) << 4)) >> 2;
  const int sw2 = ((ub + 16) ^ ((myrow & 7) << 4)) >> 2;

  int st_r[2], st_kf[2];
#pragma unroll
  for (int j = 0; j < 2; ++j) {
    int s = (wid * 2 + j) * 1024 + lane * 16;
    int r = s >> 7;
    int kb = (s & 127) ^ ((r & 7) << 4);
    st_r[j] = min(row0 + r, M - 1);
    st_kf[j] = kb >> 2;
  }

  auto stage = [&](int buf, int ks) {
#pragma unroll
    for (int j = 0; j < 2; ++j) {
      const float* src = X + (size_t)st_r[j] * 500 + ks * 32 + st_kf[j];
      __builtin_amdgcn_global_load_lds(
          (const __attribute__((address_space(1))) void*)src,
          (__attribute__((address_space(3))) void*)&xs[buf][(wid * 2 + j) * 256], 16, 0, 0);
    }
  };

  f32x4 acc[4];
#pragma unroll
  for (int nf = 0; nf < 4; ++nf) acc[nf] = (f32x4){0.f, 0.f, 0.f, 0.f};

  stage(0, 0);
  __syncthreads();

  int cur = 0;
  for (int ks = 0; ks < 15; ++ks) {
    if (ks < 14) stage(cur ^ 1, ks + 1);
    float4 p = *reinterpret_cast<const float4*>(&xs[cur][sw1]);
    float4 q = *reinterpret_cast<const float4*>(&xs[cur][sw2]);
    bf16x8 ah, al;
    split8(p, q, ah, al);
#pragma unroll
    for (int nf = 0; nf < 4; ++nf) {
      bf16x8 bh = Bhi[(ks * 4 + nf) * 64 + lane];
      bf16x8 bl = Blo[(ks * 4 + nf) * 64 + lane];
      acc[nf] = __builtin_amdgcn_mfma_f32_16x16x32_bf16(ah, bh, acc[nf], 0, 0, 0);
      acc[nf] = __builtin_amdgcn_mfma_f32_16x16x32_bf16(al, bh, acc[nf], 0, 0, 0);
      acc[nf] = __builtin_amdgcn_mfma_f32_16x16x32_bf16(ah, bl, acc[nf], 0, 0, 0);
    }
    __syncthreads();
    cur ^= 1;
  }

  {  // ks = 15 tail (k = 480..499) from guarded register loads
    const bool rowok = row0 + myrow < M;
    const float* xrow = X + (size_t)(row0 + myrow) * 500;
    float v[8];
#pragma unroll
    for (int e = 0; e < 8; ++e) {
      int k = 480 + kgrp * 8 + e;
      v[e] = (rowok && k < 500) ? xrow[k] : 0.f;
    }
    bf16x8 ah, al;
#pragma unroll
    for (int e = 0; e < 8; ++e) {
      __bf16 h = (__bf16)v[e];
      ah[e] = h;
      al[e] = (__bf16)(v[e] - (float)h);
    }
#pragma unroll
    for (int nf = 0; nf < 4; ++nf) {
      bf16x8 bh = Bhi[(15 * 4 + nf) * 64 + lane];
      bf16x8 bl = Blo[(15 * 4 + nf) * 64 + lane];
      acc[nf] = __builtin_amdgcn_mfma_f32_16x16x32_bf16(ah, bh, acc[nf], 0, 0, 0);
      acc[nf] = __builtin_amdgcn_mfma_f32_16x16x32_bf16(al, bh, acc[nf], 0, 0, 0);
      acc[nf] = __builtin_amdgcn_mfma_f32_16x16x32_bf16(ah, bl, acc[nf], 0, 0, 0);
    }
  }

  const int colw = lane & 15;
#pragma unroll
  for (int r = 0; r < 4; ++r) {
    int rowd = row0 + wid * 16 + (lane >> 4) * 4 + r;
    if (rowd >= M) continue;
#pragma unroll
    for (int nf = 0; nf < 4; ++nf) {
      float fv = acc[nf][r];
      out[(size_t)rowd * 64 + nf * 16 + colw] = fv;
      outb[(size_t)rowd * 64 + nf * 16 + colw] = (__bf16)fv;
    }
  }
}

// ---------------- dense fp32 GEMM (layer 2) ----------------

__global__ __launch_bounds__(256) void k_transpose_w(const float* __restrict__ W, float* __restrict__ Wt,
                                                     int OUTC, int K, int Kpad) {
  int idx = blockIdx.x * 256 + threadIdx.x;
  int k = idx >> 6, c = idx & 63;
  if (k < Kpad) Wt[k * 64 + c] = (k < K && c < OUTC) ? W[(size_t)c * K + k] : 0.f;
}

// Layer-2 GEMM. Writes fp32 [M,56] (for alpha) AND head-padded bf16 [M,64]
// (features h*8+c, pad c=7 zeroed) for the vectorized gather.
template <bool ELU_IN>
__global__ __launch_bounds__(256) void k_gemm(const float* __restrict__ X, const float* __restrict__ Wt,
                                              const float* __restrict__ bias, float* __restrict__ out,
                                              __bf16* __restrict__ outb,
                                              int M, int K, int ldx, int OUTN, int ksteps) {
  __shared__ __align__(16) float xs[32][132];
  __shared__ __align__(16) float ws[32][64];
  const int t = threadIdx.x;
  const int rowg = t >> 4, colg = t & 15;
  const int brow = blockIdx.x * 128;
  float acc[8][4] = {};

  for (int ks = 0; ks < ksteps; ++ks) {
    const int k0 = ks * 32;
#pragma unroll
    for (int i = 0; i < 4; ++i) {
      int f = t + i * 256;
      int r = f >> 3, kq = f & 7;
      int grow = brow + r, gk = k0 + kq * 4;
      float4 v = {0.f, 0.f, 0.f, 0.f};
      if (grow < M && gk < K) {
        v = *reinterpret_cast<const float4*>(X + (size_t)grow * ldx + gk);
        if (ELU_IN) {
          v.x = eluf(v.x + bias[gk + 0]);
          v.y = eluf(v.y + bias[gk + 1]);
          v.z = eluf(v.z + bias[gk + 2]);
          v.w = eluf(v.w + bias[gk + 3]);
        }
      }
      xs[kq * 4 + 0][r] = v.x;
      xs[kq * 4 + 1][r] = v.y;
      xs[kq * 4 + 2][r] = v.z;
      xs[kq * 4 + 3][r] = v.w;
    }
#pragma unroll
    for (int i = 0; i < 2; ++i) {
      int f = t + i * 256;
      int kk = f >> 4, c4 = (f & 15) * 4;
      *reinterpret_cast<float4*>(&ws[kk][c4]) =
          *reinterpret_cast<const float4*>(Wt + (size_t)(k0 + kk) * 64 + c4);
    }
    __syncthreads();
#pragma unroll
    for (int k = 0; k < 32; ++k) {
      float4 xa = *reinterpret_cast<const float4*>(&xs[k][rowg * 8]);
      float4 xb = *reinterpret_cast<const float4*>(&xs[k][rowg * 8 + 4]);
      float4 wv = *reinterpret_cast<const float4*>(&ws[k][colg * 4]);
      float xr[8] = {xa.x, xa.y, xa.z, xa.w, xb.x, xb.y, xb.z, xb.w};
      float wc[4] = {wv.x, wv.y, wv.z, wv.w};
#pragma unroll
      for (int r = 0; r < 8; ++r)
#pragma unroll
        for (int c = 0; c < 4; ++c) acc[r][c] = fmaf(xr[r], wc[c], acc[r][c]);
    }
    __syncthreads();
  }

#pragma unroll
  for (int r = 0; r < 8; ++r) {
    int grow = brow + rowg * 8 + r;
    if (grow >= M) continue;
#pragma unroll
    for (int c = 0; c < 4; ++c) {
      int col = colg * 4 + c;
      if (col < OUTN) {
        float fv = acc[r][c];
        out[(size_t)grow * OUTN + col] = fv;
        int hh = col / 7, cc = col - hh * 7;
        outb[(size_t)grow * 64 + hh * 8 + cc] = (__bf16)fv;
      }
    }
    if (colg == 14) {  // cols 56..59 unused -> zero the 8 pad slots (ws is 0xAA-poisoned)
#pragma unroll
      for (int hh = 0; hh < 8; ++hh) outb[(size_t)grow * 64 + hh * 8 + 7] = (__bf16)0.f;
    }
  }
}

// alpha_s / alpha_d: per (node, head) dot of h[node, head*D..] with att vectors.
template <int D, int F>
__global__ __launch_bounds__(256) void k_alpha(const float* __restrict__ h, const float* __restrict__ a_src,
                                               const float* __restrict__ a_dst, float* __restrict__ as_,
                                               float* __restrict__ ad_, int N) {
  int idx = blockIdx.x * 256 + threadIdx.x;
  int node = idx >> 3, head = idx & 7;
  if (node >= N) return;
  const float* hr = h + (size_t)node * F + head * D;
  float ss = 0.f, sd = 0.f;
#pragma unroll
  for (int d = 0; d < D; ++d) {
    float v = hr[d];
    ss = fmaf(v, a_src[head * D + d], ss);
    sd = fmaf(v, a_dst[head * D + d], sd);
  }
  as_[idx] = ss;
  ad_[idx] = sd;
}

// Layer-1 aggregation, vectorized pass 2: lane = (slot g = lane>>3, head = lane&7);
// 8 edges/iteration, uint4 gather of 8 bf16 features, bit-shift conversion.
// After pass-1 butterfly every lane already holds m/den for head lane&7.
__global__ __launch_bounds__(256) void k_agg1v(const unsigned short* __restrict__ hb,
                                               const float* __restrict__ as_,
                                               const float* __restrict__ ad_,
                                               const int* __restrict__ rowptr,
                                               const int* __restrict__ csr,
                                               float* __restrict__ o1, int N) {
  const int lane = threadIdx.x & 63;
  const int n = blockIdx.x * 4 + (threadIdx.x >> 6);
  if (n >= N) return;
  const int r0 = rowptr[n], r1 = rowptr[n + 1];
  const int head = lane & 7;
  const int slot = lane >> 3;
  const float ad_h = ad_[(size_t)n * 8 + head];

  float m = -1e30f, den = 0.f;
  for (int j = r0 + slot; j < r1; j += 8) {
    int s = csr[j];
    float e = lreluf(as_[(size_t)s * 8 + head] + ad_h);
    float nm = fmaxf(m, e);
    den = den * __expf(m - nm) + __expf(e - nm);
    m = nm;
  }
#pragma unroll
  for (int off = 8; off < 64; off <<= 1) {
    float mo = __shfl_xor(m, off);
    float dn = __shfl_xor(den, off);
    float nm = fmaxf(m, mo);
    den = den * __expf(m - nm) + dn * __expf(mo - nm);
    m = nm;
  }
  const float inv_den = 1.f / den;

  f32x4 accA = {0.f, 0.f, 0.f, 0.f}, accB = {0.f, 0.f, 0.f, 0.f};
  for (int j = r0 + slot; j < r1; j += 8) {
    int s = csr[j];
    float a = as_[(size_t)s * 8 + head];
    uint4 w = *reinterpret_cast<const uint4*>(hb + (size_t)s * 64 + head * 8);
    float p = __expf(lreluf(a + ad_h) - m);
    accA[0] = fmaf(p, bflo(w.x), accA[0]);
    accA[1] = fmaf(p, bfhi(w.x), accA[1]);
    accA[2] = fmaf(p, bflo(w.y), accA[2]);
    accA[3] = fmaf(p, bfhi(w.y), accA[3]);
    accB[0] = fmaf(p, bflo(w.z), accB[0]);
    accB[1] = fmaf(p, bfhi(w.z), accB[1]);
    accB[2] = fmaf(p, bflo(w.w), accB[2]);
    accB[3] = fmaf(p, bfhi(w.w), accB[3]);
  }
#pragma unroll
  for (int off = 8; off < 64; off <<= 1) {
#pragma unroll
    for (int k = 0; k < 4; ++k) {
      accA[k] += __shfl_xor(accA[k], off);
      accB[k] += __shfl_xor(accB[k], off);
    }
  }
  if (lane < 8) {
    float4 oA = {accA[0] * inv_den, accA[1] * inv_den, accA[2] * inv_den, accA[3] * inv_den};
    float4 oB = {accB[0] * inv_den, accB[1] * inv_den, accB[2] * inv_den, accB[3] * inv_den};
    *reinterpret_cast<float4*>(o1 + (size_t)n * 64 + lane * 8) = oA;
    *reinterpret_cast<float4*>(o1 + (size_t)n * 64 + lane * 8 + 4) = oB;
  }
}

// Layer-2 aggregation, vectorized pass 2 on head-padded bf16 h [N,64]:
// lane = (slot g = lane>>4, l = lane&15), head = l>>1, uint2 gather (4 features),
// 4 edges/iteration. Output written unpadded [N,56] + bias.
__global__ __launch_bounds__(256) void k_agg2v(const unsigned short* __restrict__ hb,
                                               const float* __restrict__ as_,
                                               const float* __restrict__ ad_,
                                               const int* __restrict__ rowptr,
                                               const int* __restrict__ csr,
                                               const float* __restrict__ bias,
                                               float* __restrict__ out, int N) {
  const int lane = threadIdx.x & 63;
  const int n = blockIdx.x * 4 + (threadIdx.x >> 6);
  if (n >= N) return;
  const int r0 = rowptr[n], r1 = rowptr[n + 1];
  const int head = lane & 7;
  const float ad_h = ad_[(size_t)n * 8 + head];

  float m = -1e30f, den = 0.f;
  for (int j = r0 + (lane >> 3); j < r1; j += 8) {
    int s = csr[j];
    float e = lreluf(as_[(size_t)s * 8 + head] + ad_h);
    float nm = fmaxf(m, e);
    den = den * __expf(m - nm) + __expf(e - nm);
    m = nm;
  }
#pragma unroll
  for (int off = 8; off < 64; off <<= 1) {
    float mo = __shfl_xor(m, off);
    float dn = __shfl_xor(den, off);
    float nm = fmaxf(m, mo);
    den = den * __expf(m - nm) + dn * __expf(mo - nm);
    m = nm;
  }
  const float inv_den = 1.f / den;

  const int l = lane & 15, slot = lane >> 4;
  const int h2 = l >> 1;
  const float m_h = __shfl(m, h2);
  const float id_h = __shfl(inv_den, h2);
  const float ad2 = __shfl(ad_h, h2);

  f32x4 acc = {0.f, 0.f, 0.f, 0.f};
  for (int j = r0 + slot; j < r1; j += 4) {
    int s = csr[j];
    float a = as_[(size_t)s * 8 + h2];
    uint2 w = *reinterpret_cast<const uint2*>(hb + (size_t)s * 64 + l * 4);
    float p = __expf(lreluf(a + ad2) - m_h);
    acc[0] = fmaf(p, bflo(w.x), acc[0]);
    acc[1] = fmaf(p, bfhi(w.x), acc[1]);
    acc[2] = fmaf(p, bflo(w.y), acc[2]);
    acc[3] = fmaf(p, bfhi(w.y), acc[3]);
  }
#pragma unroll
  for (int off = 16; off < 64; off <<= 1)
#pragma unroll
    for (int k = 0; k < 4; ++k) acc[k] += __shfl_xor(acc[k], off);

  if (lane < 16) {
    int c0 = (l & 1) * 4;
#pragma unroll
    for (int r = 0; r < 4; ++r) {
      int c = c0 + r;
      if (c < 7) out[(size_t)n * 56 + h2 * 7 + c] = acc[r] * id_h + bias[h2 * 7 + c];
    }
  }
}

// ---------------- launch ----------------

extern "C" void kernel_launch(void* const* d_in, const int* in_sizes, int n_in,
                              void* d_out, int out_size, void* d_ws, size_t ws_size,
                              hipStream_t stream) {
  const float* x    = (const float*)d_in[0];
  const int*   ei   = (const int*)d_in[1];
  const float* W1   = (const float*)d_in[2];
  const float* at_s1 = (const float*)d_in[3];
  const float* at_d1 = (const float*)d_in[4];
  const float* b1   = (const float*)d_in[5];
  const float* W2   = (const float*)d_in[6];
  const float* at_s2 = (const float*)d_in[7];
  const float* at_d2 = (const float*)d_in[8];
  const float* b2   = (const float*)d_in[9];
  float* out = (float*)d_out;

  const int N = in_sizes[0] / 500;
  const int E = in_sizes[1] / 2;

  char* w = (char*)d_ws;
  auto alloc = [&](size_t bytes) -> void* {
    void* p = (void*)w;
    w += (bytes + 255) & ~(size_t)255;
    return p;
  };
  int*   rowptr = (int*)alloc((size_t)(N + 1) * 4);
  int*   cursor = (int*)alloc((size_t)N * 4);
  int*   deg    = (int*)alloc((size_t)N * 4);
  int*   flag   = (int*)alloc(256);
  int*   bsum   = (int*)alloc(4096);
  int*   boff   = (int*)alloc(4096);
  int*   ei_c   = (int*)alloc((size_t)2 * E * 4);
  int*   csr    = (int*)alloc((size_t)(E + N) * 4);
  float* h1     = (float*)alloc((size_t)N * 64 * 4);  // layer-1 h fp32; reused as layer-2 h fp32 [N,56]
  float* o1     = (float*)alloc((size_t)N * 64 * 4);
  float* asb    = (float*)alloc((size_t)N * 8 * 4);
  float* adb    = (float*)alloc((size_t)N * 8 * 4);
  float* Wt2    = (float*)alloc((size_t)64 * 64 * 4);
  __bf16* Bhi1  = (__bf16*)alloc((size_t)32768 * 2);
  __bf16* Blo1  = (__bf16*)alloc((size_t)32768 * 2);
  __bf16* h1b   = (__bf16*)alloc((size_t)N * 64 * 2);  // layer-1 h bf16 [N,64]
  __bf16* h2b   = (__bf16*)alloc((size_t)N * 64 * 2);  // layer-2 h bf16 head-padded [N,64]

  auto cdiv = [](int a, int b) { return (a + b - 1) / b; };
  const int nbN = cdiv(N, 256);

  // CSR build (shared by both layers: same graph + self-loops)
  k_init<<<nbN, 256, 0, stream>>>(deg, flag, N);
  k_detect<<<cdiv(50000, 256), 256, 0, stream>>>(ei, flag, 50000);
  k_convert<<<cdiv(2 * E, 256), 256, 0, stream>>>(ei, flag, ei_c, 2 * E);
  k_count<<<cdiv(E, 256), 256, 0, stream>>>(ei_c, deg, E);
  k_blocksum<<<nbN, 256, 0, stream>>>(deg, bsum, N);
  k_scan_bsum<<<1, 512, 0, stream>>>(bsum, boff, nbN, rowptr, N);
  k_scan_final<<<nbN, 256, 0, stream>>>(deg, boff, rowptr, cursor, N);
  {
    const int G = 768;
    k_fill_shard<<<8 * G, 256, 0, stream>>>(ei_c, cursor, csr, E, N, cdiv(E + N, G));
  }

  // Layer 1
  k_prep_b1<<<cdiv(32768, 256), 256, 0, stream>>>(W1, Bhi1, Blo1);
  k_gemm1_lds<<<cdiv(N, 64), 256, 0, stream>>>(x, (const bf16x8*)Bhi1, (const bf16x8*)Blo1, h1, h1b, N);
  k_alpha<8, 64><<<cdiv(N * 8, 256), 256, 0, stream>>>(h1, at_s1, at_d1, asb, adb, N);
  k_agg1v<<<cdiv(N, 4), 256, 0, stream>>>((const unsigned short*)h1b, asb, adb, rowptr, csr, o1, N);

  // Layer 2 (bias b1 + ELU fused into GEMM2 input load)
  k_transpose_w<<<cdiv(64 * 64, 256), 256, 0, stream>>>(W2, Wt2, 56, 64, 64);
  k_gemm<true><<<cdiv(N, 128), 256, 0, stream>>>(o1, Wt2, b1, h1, h2b, N, 64, 64, 56, 2);
  k_alpha<7, 56><<<cdiv(N * 8, 256), 256, 0, stream>>>(h1, at_s2, at_d2, asb, adb, N);
  k_agg2v<<<cdiv(N, 4), 256, 0, stream>>>((const unsigned short*)h2b, asb, adb, rowptr, csr, b2, out, N);
}

// Round 8
// 412.448 us; speedup vs baseline: 1.2528x; 1.1251x over previous
//
#include <hip/hip_runtime.h>

#define NEG_SLOPE 0.2f

typedef __bf16 bf16x8 __attribute__((ext_vector_type(8)));
typedef float f32x4 __attribute__((ext_vector_type(4)));

__device__ __forceinline__ float eluf(float x) { return x > 0.f ? x : __expf(x) - 1.f; }
__device__ __forceinline__ float lreluf(float x) { return x > 0.f ? x : NEG_SLOPE * x; }
__device__ __forceinline__ float bflo(unsigned u) { return __uint_as_float(u << 16); }
__device__ __forceinline__ float bfhi(unsigned u) { return __uint_as_float(u & 0xffff0000u); }

__device__ __forceinline__ void split8(const float4& p, const float4& q, bf16x8& hi, bf16x8& lo) {
  float v[8] = {p.x, p.y, p.z, p.w, q.x, q.y, q.z, q.w};
#pragma unroll
  for (int e = 0; e < 8; ++e) {
    __bf16 h = (__bf16)v[e];
    hi[e] = h;
    lo[e] = (__bf16)(v[e] - (float)h);
  }
}

// ---------------- CSR build ----------------

__global__ __launch_bounds__(256) void k_init(int* __restrict__ deg, int* __restrict__ flag, int N) {
  int i = blockIdx.x * 256 + threadIdx.x;
  if (i < N) deg[i] = 1;  // self-loop
  if (i == 0) *flag = 0;
}

// If edge_index arrived as int64, every odd int32 word is 0 (values < 2^31).
__global__ __launch_bounds__(256) void k_detect(const int* __restrict__ raw, int* __restrict__ flag, int nCheck) {
  int i = blockIdx.x * 256 + threadIdx.x;
  if (i < nCheck && raw[2 * i + 1] != 0) atomicOr(flag, 1);
}

// Convert (int64|int32) -> int32 AND count dst degrees (i >= E is the dst half).
__global__ __launch_bounds__(256) void k_convert(const int* __restrict__ raw, const int* __restrict__ flag,
                                                 int* __restrict__ out, int* __restrict__ deg, int n, int E) {
  int i = blockIdx.x * 256 + threadIdx.x;
  if (i >= n) return;
  bool is32 = (*flag != 0);
  int v = is32 ? raw[i] : raw[2 * i];
  out[i] = v;
  if (i >= E) atomicAdd(&deg[v], 1);
}

__global__ __launch_bounds__(256) void k_blocksum(const int* __restrict__ deg, int* __restrict__ bsum, int N) {
  __shared__ int s[256];
  int t = threadIdx.x;
  int i = blockIdx.x * 256 + t;
  s[t] = (i < N) ? deg[i] : 0;
  __syncthreads();
  for (int off = 128; off > 0; off >>= 1) {
    if (t < off) s[t] += s[t + off];
    __syncthreads();
  }
  if (t == 0) bsum[blockIdx.x] = s[0];
}

__global__ __launch_bounds__(512) void k_scan_bsum(const int* __restrict__ bsum, int* __restrict__ boff,
                                                   int nb, int* __restrict__ rowptr, int N) {
  __shared__ int s[512];
  int t = threadIdx.x;
  int v = (t < nb) ? bsum[t] : 0;
  s[t] = v;
  __syncthreads();
  for (int off = 1; off < 512; off <<= 1) {
    int u = (t >= off) ? s[t - off] : 0;
    __syncthreads();
    s[t] += u;
    __syncthreads();
  }
  if (t < nb) boff[t] = s[t] - v;       // exclusive
  if (t == nb - 1) rowptr[N] = s[t];    // total = E + N
}

__global__ __launch_bounds__(256) void k_scan_final(const int* __restrict__ deg, const int* __restrict__ boff,
                                                    int* __restrict__ rowptr, int* __restrict__ cursor, int N) {
  __shared__ int s[256];
  int t = threadIdx.x;
  int i = blockIdx.x * 256 + t;
  int v = (i < N) ? deg[i] : 0;
  s[t] = v;
  __syncthreads();
  for (int off = 1; off < 256; off <<= 1) {
    int u = (t >= off) ? s[t - off] : 0;
    __syncthreads();
    s[t] += u;
    __syncthreads();
  }
  if (i < N) {
    int ex = boff[blockIdx.x] + s[t] - v;
    rowptr[i] = ex;
    cursor[i] = ex;
  }
}

// XCD-sharded CSR fill (see R3): each XCD's csr writes stay in its own L2.
__global__ __launch_bounds__(256) void k_fill_shard(const int* __restrict__ ei, int* __restrict__ cursor,
                                                    int* __restrict__ csr, int E, int N, int CH) {
  const int shard = blockIdx.x & 7;
  const int chunk = blockIdx.x >> 3;
  const int i0 = chunk * CH;
  const int i1 = min(i0 + CH, E + N);
  for (int idx = i0 + (int)threadIdx.x; idx < i1; idx += 256) {
    int d = (idx < E) ? ei[E + idx] : idx - E;
    if (((d >> 13) & 7) != shard) continue;
    int s = (idx < E) ? ei[idx] : idx - E;
    int pos = atomicAdd(&cursor[d], 1);
    csr[pos] = s;
  }
}

// ---------------- layer-1 GEMM: split-bf16 MFMA, LDS-staged X ----------------

__global__ __launch_bounds__(256) void k_prep_b1(const float* __restrict__ W1, __bf16* __restrict__ bhi,
                                                 __bf16* __restrict__ blo) {
  int idx = blockIdx.x * 256 + threadIdx.x;  // 0 .. 16*4*64*8-1 = 32767
  if (idx >= 16 * 4 * 64 * 8) return;
  int e = idx & 7;
  int lane = (idx >> 3) & 63;
  int nf = (idx >> 9) & 3;
  int ks = idx >> 11;
  int k = ks * 32 + (lane >> 4) * 8 + e;
  int col = nf * 16 + (lane & 15);
  float w = (k < 500) ? W1[(size_t)col * 500 + k] : 0.f;
  __bf16 h = (__bf16)w;
  bhi[idx] = h;
  blo[idx] = (__bf16)(w - (float)h);
}

// C[M x 64] = X[M x 500] * W1^T via 3-term split-bf16 MFMA; emits bf16 C only.
__global__ __launch_bounds__(256) void k_gemm1_lds(const float* __restrict__ X, const bf16x8* __restrict__ Bhi,
                                                   const bf16x8* __restrict__ Blo,
                                                   __bf16* __restrict__ outb, int M) {
  __shared__ __align__(16) float xs[2][2048];
  const int lane = threadIdx.x & 63;
  const int wid = threadIdx.x >> 6;
  const int row0 = blockIdx.x * 64;
  const int kgrp = lane >> 4;
  const int rloc = lane & 15;
  const int myrow = wid * 16 + rloc;

  const int ub = myrow * 128 + kgrp * 32;
  const int sw1 = (ub ^ ((myrow & 7) << 4)) >> 2;
  const int sw2 = ((ub + 16) ^ ((myrow & 7) << 4)) >> 2;

  int st_r[2], st_kf[2];
#pragma unroll
  for (int j = 0; j < 2; ++j) {
    int s = (wid * 2 + j) * 1024 + lane * 16;
    int r = s >> 7;
    int kb = (s & 127) ^ ((r & 7) << 4);
    st_r[j] = min(row0 + r, M - 1);
    st_kf[j] = kb >> 2;
  }

  auto stage = [&](int buf, int ks) {
#pragma unroll
    for (int j = 0; j < 2; ++j) {
      const float* src = X + (size_t)st_r[j] * 500 + ks * 32 + st_kf[j];
      __builtin_amdgcn_global_load_lds(
          (const __attribute__((address_space(1))) void*)src,
          (__attribute__((address_space(3))) void*)&xs[buf][(wid * 2 + j) * 256], 16, 0, 0);
    }
  };

  f32x4 acc[4];
#pragma unroll
  for (int nf = 0; nf < 4; ++nf) acc[nf] = (f32x4){0.f, 0.f, 0.f, 0.f};

  stage(0, 0);
  __syncthreads();

  int cur = 0;
  for (int ks = 0; ks < 15; ++ks) {
    if (ks < 14) stage(cur ^ 1, ks + 1);
    float4 p = *reinterpret_cast<const float4*>(&xs[cur][sw1]);
    float4 q = *reinterpret_cast<const float4*>(&xs[cur][sw2]);
    bf16x8 ah, al;
    split8(p, q, ah, al);
#pragma unroll
    for (int nf = 0; nf < 4; ++nf) {
      bf16x8 bh = Bhi[(ks * 4 + nf) * 64 + lane];
      bf16x8 bl = Blo[(ks * 4 + nf) * 64 + lane];
      acc[nf] = __builtin_amdgcn_mfma_f32_16x16x32_bf16(ah, bh, acc[nf], 0, 0, 0);
      acc[nf] = __builtin_amdgcn_mfma_f32_16x16x32_bf16(al, bh, acc[nf], 0, 0, 0);
      acc[nf] = __builtin_amdgcn_mfma_f32_16x16x32_bf16(ah, bl, acc[nf], 0, 0, 0);
    }
    __syncthreads();
    cur ^= 1;
  }

  {  // ks = 15 tail (k = 480..499) from guarded register loads
    const bool rowok = row0 + myrow < M;
    const float* xrow = X + (size_t)(row0 + myrow) * 500;
    float v[8];
#pragma unroll
    for (int e = 0; e < 8; ++e) {
      int k = 480 + kgrp * 8 + e;
      v[e] = (rowok && k < 500) ? xrow[k] : 0.f;
    }
    bf16x8 ah, al;
#pragma unroll
    for (int e = 0; e < 8; ++e) {
      __bf16 h = (__bf16)v[e];
      ah[e] = h;
      al[e] = (__bf16)(v[e] - (float)h);
    }
#pragma unroll
    for (int nf = 0; nf < 4; ++nf) {
      bf16x8 bh = Bhi[(15 * 4 + nf) * 64 + lane];
      bf16x8 bl = Blo[(15 * 4 + nf) * 64 + lane];
      acc[nf] = __builtin_amdgcn_mfma_f32_16x16x32_bf16(ah, bh, acc[nf], 0, 0, 0);
      acc[nf] = __builtin_amdgcn_mfma_f32_16x16x32_bf16(al, bh, acc[nf], 0, 0, 0);
      acc[nf] = __builtin_amdgcn_mfma_f32_16x16x32_bf16(ah, bl, acc[nf], 0, 0, 0);
    }
  }

  const int colw = lane & 15;
#pragma unroll
  for (int r = 0; r < 4; ++r) {
    int rowd = row0 + wid * 16 + (lane >> 4) * 4 + r;
    if (rowd >= M) continue;
#pragma unroll
    for (int nf = 0; nf < 4; ++nf)
      outb[(size_t)rowd * 64 + nf * 16 + colw] = (__bf16)acc[nf][r];
  }
}

// ---------------- dense fp32 GEMM (layer 2) ----------------

__global__ __launch_bounds__(256) void k_transpose_w(const float* __restrict__ W, float* __restrict__ Wt,
                                                     int OUTC, int K, int Kpad) {
  int idx = blockIdx.x * 256 + threadIdx.x;
  int k = idx >> 6, c = idx & 63;
  if (k < Kpad) Wt[k * 64 + c] = (k < K && c < OUTC) ? W[(size_t)c * K + k] : 0.f;
}

// Layer-2 GEMM. Writes ONLY head-padded bf16 [M,64] (features h*8+c, pad c=7 zeroed).
template <bool ELU_IN>
__global__ __launch_bounds__(256) void k_gemm(const float* __restrict__ X, const float* __restrict__ Wt,
                                              const float* __restrict__ bias,
                                              __bf16* __restrict__ outb,
                                              int M, int K, int ldx, int OUTN, int ksteps) {
  __shared__ __align__(16) float xs[32][132];
  __shared__ __align__(16) float ws[32][64];
  const int t = threadIdx.x;
  const int rowg = t >> 4, colg = t & 15;
  const int brow = blockIdx.x * 128;
  float acc[8][4] = {};

  for (int ks = 0; ks < ksteps; ++ks) {
    const int k0 = ks * 32;
#pragma unroll
    for (int i = 0; i < 4; ++i) {
      int f = t + i * 256;
      int r = f >> 3, kq = f & 7;
      int grow = brow + r, gk = k0 + kq * 4;
      float4 v = {0.f, 0.f, 0.f, 0.f};
      if (grow < M && gk < K) {
        v = *reinterpret_cast<const float4*>(X + (size_t)grow * ldx + gk);
        if (ELU_IN) {
          v.x = eluf(v.x + bias[gk + 0]);
          v.y = eluf(v.y + bias[gk + 1]);
          v.z = eluf(v.z + bias[gk + 2]);
          v.w = eluf(v.w + bias[gk + 3]);
        }
      }
      xs[kq * 4 + 0][r] = v.x;
      xs[kq * 4 + 1][r] = v.y;
      xs[kq * 4 + 2][r] = v.z;
      xs[kq * 4 + 3][r] = v.w;
    }
#pragma unroll
    for (int i = 0; i < 2; ++i) {
      int f = t + i * 256;
      int kk = f >> 4, c4 = (f & 15) * 4;
      *reinterpret_cast<float4*>(&ws[kk][c4]) =
          *reinterpret_cast<const float4*>(Wt + (size_t)(k0 + kk) * 64 + c4);
    }
    __syncthreads();
#pragma unroll
    for (int k = 0; k < 32; ++k) {
      float4 xa = *reinterpret_cast<const float4*>(&xs[k][rowg * 8]);
      float4 xb = *reinterpret_cast<const float4*>(&xs[k][rowg * 8 + 4]);
      float4 wv = *reinterpret_cast<const float4*>(&ws[k][colg * 4]);
      float xr[8] = {xa.x, xa.y, xa.z, xa.w, xb.x, xb.y, xb.z, xb.w};
      float wc[4] = {wv.x, wv.y, wv.z, wv.w};
#pragma unroll
      for (int r = 0; r < 8; ++r)
#pragma unroll
        for (int c = 0; c < 4; ++c) acc[r][c] = fmaf(xr[r], wc[c], acc[r][c]);
    }
    __syncthreads();
  }

#pragma unroll
  for (int r = 0; r < 8; ++r) {
    int grow = brow + rowg * 8 + r;
    if (grow >= M) continue;
#pragma unroll
    for (int c = 0; c < 4; ++c) {
      int col = colg * 4 + c;
      if (col < OUTN) {
        int hh = col / 7, cc = col - hh * 7;
        outb[(size_t)grow * 64 + hh * 8 + cc] = (__bf16)acc[r][c];
      }
    }
    if (colg == 14) {  // zero the 8 pad slots (ws is 0xAA-poisoned)
#pragma unroll
      for (int hh = 0; hh < 8; ++hh) outb[(size_t)grow * 64 + hh * 8 + 7] = (__bf16)0.f;
    }
  }
}

// alpha from bf16 h rows (one uint4 = 8 slots per (node,head)); D = valid slots.
template <int D>
__global__ __launch_bounds__(256) void k_alpha_b(const unsigned short* __restrict__ hb,
                                                 const float* __restrict__ a_src,
                                                 const float* __restrict__ a_dst,
                                                 float* __restrict__ as_, float* __restrict__ ad_, int N) {
  int idx = blockIdx.x * 256 + threadIdx.x;
  int node = idx >> 3, head = idx & 7;
  if (node >= N) return;
  uint4 w = *reinterpret_cast<const uint4*>(hb + (size_t)node * 64 + head * 8);
  float v[8] = {bflo(w.x), bfhi(w.x), bflo(w.y), bfhi(w.y),
                bflo(w.z), bfhi(w.z), bflo(w.w), bfhi(w.w)};
  float ss = 0.f, sd = 0.f;
#pragma unroll
  for (int d = 0; d < D; ++d) {
    ss = fmaf(v[d], a_src[head * D + d], ss);
    sd = fmaf(v[d], a_dst[head * D + d], sd);
  }
  as_[idx] = ss;
  ad_[idx] = sd;
}

// Layer-1 aggregation: lane = (slot = lane>>3, head = lane&7).
// Pass1 buffers e and src-id in static-unrolled registers (deg<=48); pass2
// reuses them (no as_ re-read, no lrelu) with 6 independent predicated gathers.
__global__ __launch_bounds__(256) void k_agg1v(const unsigned short* __restrict__ hb,
                                               const float* __restrict__ as_,
                                               const float* __restrict__ ad_,
                                               const int* __restrict__ rowptr,
                                               const int* __restrict__ csr,
                                               float* __restrict__ o1, int N) {
  const int lane = threadIdx.x & 63;
  const int n = blockIdx.x * 4 + (threadIdx.x >> 6);
  if (n >= N) return;
  const int r0 = rowptr[n], r1 = rowptr[n + 1];
  const int head = lane & 7;
  const int slot = lane >> 3;
  const float ad_h = ad_[(size_t)n * 8 + head];

  float m = -1e30f, den = 0.f;
  float eb[6];
  int sb[6];
#pragma unroll
  for (int i = 0; i < 6; ++i) {
    int j = r0 + slot + i * 8;
    bool ok = j < r1;
    int s = ok ? csr[j] : 0;
    sb[i] = s;
    float e = lreluf(as_[(size_t)s * 8 + head] + ad_h);
    eb[i] = e;
    float nm = ok ? fmaxf(m, e) : m;
    den = den * __expf(m - nm) + (ok ? __expf(e - nm) : 0.f);
    m = nm;
  }
  for (int j = r0 + slot + 48; j < r1; j += 8) {  // rare tail (deg > 48)
    int s = csr[j];
    float e = lreluf(as_[(size_t)s * 8 + head] + ad_h);
    float nm = fmaxf(m, e);
    den = den * __expf(m - nm) + __expf(e - nm);
    m = nm;
  }
#pragma unroll
  for (int off = 8; off < 64; off <<= 1) {
    float mo = __shfl_xor(m, off);
    float dn = __shfl_xor(den, off);
    float nm = fmaxf(m, mo);
    den = den * __expf(m - nm) + dn * __expf(mo - nm);
    m = nm;
  }
  const float inv_den = 1.f / den;

  f32x4 accA = {0.f, 0.f, 0.f, 0.f}, accB = {0.f, 0.f, 0.f, 0.f};
#pragma unroll
  for (int i = 0; i < 6; ++i) {
    int j = r0 + slot + i * 8;
    if (j < r1) {
      uint4 w = *reinterpret_cast<const uint4*>(hb + (size_t)sb[i] * 64 + head * 8);
      float p = __expf(eb[i] - m);
      accA[0] = fmaf(p, bflo(w.x), accA[0]);
      accA[1] = fmaf(p, bfhi(w.x), accA[1]);
      accA[2] = fmaf(p, bflo(w.y), accA[2]);
      accA[3] = fmaf(p, bfhi(w.y), accA[3]);
      accB[0] = fmaf(p, bflo(w.z), accB[0]);
      accB[1] = fmaf(p, bfhi(w.z), accB[1]);
      accB[2] = fmaf(p, bflo(w.w), accB[2]);
      accB[3] = fmaf(p, bfhi(w.w), accB[3]);
    }
  }
  for (int j = r0 + slot + 48; j < r1; j += 8) {  // rare tail
    int s = csr[j];
    float a = as_[(size_t)s * 8 + head];
    uint4 w = *reinterpret_cast<const uint4*>(hb + (size_t)s * 64 + head * 8);
    float p = __expf(lreluf(a + ad_h) - m);
    accA[0] = fmaf(p, bflo(w.x), accA[0]);
    accA[1] = fmaf(p, bfhi(w.x), accA[1]);
    accA[2] = fmaf(p, bflo(w.y), accA[2]);
    accA[3] = fmaf(p, bfhi(w.y), accA[3]);
    accB[0] = fmaf(p, bflo(w.z), accB[0]);
    accB[1] = fmaf(p, bfhi(w.z), accB[1]);
    accB[2] = fmaf(p, bflo(w.w), accB[2]);
    accB[3] = fmaf(p, bfhi(w.w), accB[3]);
  }
#pragma unroll
  for (int off = 8; off < 64; off <<= 1) {
#pragma unroll
    for (int k = 0; k < 4; ++k) {
      accA[k] += __shfl_xor(accA[k], off);
      accB[k] += __shfl_xor(accB[k], off);
    }
  }
  if (lane < 8) {
    float4 oA = {accA[0] * inv_den, accA[1] * inv_den, accA[2] * inv_den, accA[3] * inv_den};
    float4 oB = {accB[0] * inv_den, accB[1] * inv_den, accB[2] * inv_den, accB[3] * inv_den};
    *reinterpret_cast<float4*>(o1 + (size_t)n * 64 + lane * 8) = oA;
    *reinterpret_cast<float4*>(o1 + (size_t)n * 64 + lane * 8 + 4) = oB;
  }
}

// Layer-2 aggregation on head-padded bf16 h [N,64]. Pass1 uses PASS2's lane
// mapping (slot = lane>>4, l = lane&15, head = l>>1; each (edge,head) computed
// by 2 lanes — redundant VALU, same bytes) so e/src buffer in registers
// (deg<=32; tail refetches). Butterfly merges the 4 slots (xor 16,32) only.
__global__ __launch_bounds__(256) void k_agg2v(const unsigned short* __restrict__ hb,
                                               const float* __restrict__ as_,
                                               const float* __restrict__ ad_,
                                               const int* __restrict__ rowptr,
                                               const int* __restrict__ csr,
                                               const float* __restrict__ bias,
                                               float* __restrict__ out, int N) {
  const int lane = threadIdx.x & 63;
  const int n = blockIdx.x * 4 + (threadIdx.x >> 6);
  if (n >= N) return;
  const int r0 = rowptr[n], r1 = rowptr[n + 1];
  const int l = lane & 15, slot = lane >> 4, h2 = l >> 1;
  const float ad2 = ad_[(size_t)n * 8 + h2];

  float m = -1e30f, den = 0.f;
  float eb[8];
  int sb[8];
#pragma unroll
  for (int i = 0; i < 8; ++i) {
    int j = r0 + slot + i * 4;
    bool ok = j < r1;
    int s = ok ? csr[j] : 0;
    sb[i] = s;
    float e = lreluf(as_[(size_t)s * 8 + h2] + ad2);
    eb[i] = e;
    float nm = ok ? fmaxf(m, e) : m;
    den = den * __expf(m - nm) + (ok ? __expf(e - nm) : 0.f);
    m = nm;
  }
  for (int j = r0 + slot + 32; j < r1; j += 4) {  // rare tail (deg > 32)
    int s = csr[j];
    float e = lreluf(as_[(size_t)s * 8 + h2] + ad2);
    float nm = fmaxf(m, e);
    den = den * __expf(m - nm) + __expf(e - nm);
    m = nm;
  }
#pragma unroll
  for (int off = 16; off < 64; off <<= 1) {
    float mo = __shfl_xor(m, off);
    float dn = __shfl_xor(den, off);
    float nm = fmaxf(m, mo);
    den = den * __expf(m - nm) + dn * __expf(mo - nm);
    m = nm;
  }
  const float inv_den = 1.f / den;

  f32x4 acc = {0.f, 0.f, 0.f, 0.f};
#pragma unroll
  for (int i = 0; i < 8; ++i) {
    int j = r0 + slot + i * 4;
    if (j < r1) {
      uint2 w = *reinterpret_cast<const uint2*>(hb + (size_t)sb[i] * 64 + l * 4);
      float p = __expf(eb[i] - m);
      acc[0] = fmaf(p, bflo(w.x), acc[0]);
      acc[1] = fmaf(p, bfhi(w.x), acc[1]);
      acc[2] = fmaf(p, bflo(w.y), acc[2]);
      acc[3] = fmaf(p, bfhi(w.y), acc[3]);
    }
  }
  for (int j = r0 + slot + 32; j < r1; j += 4) {  // rare tail
    int s = csr[j];
    float a = as_[(size_t)s * 8 + h2];
    uint2 w = *reinterpret_cast<const uint2*>(hb + (size_t)s * 64 + l * 4);
    float p = __expf(lreluf(a + ad2) - m);
    acc[0] = fmaf(p, bflo(w.x), acc[0]);
    acc[1] = fmaf(p, bfhi(w.x), acc[1]);
    acc[2] = fmaf(p, bflo(w.y), acc[2]);
    acc[3] = fmaf(p, bfhi(w.y), acc[3]);
  }
#pragma unroll
  for (int off = 16; off < 64; off <<= 1)
#pragma unroll
    for (int k = 0; k < 4; ++k) acc[k] += __shfl_xor(acc[k], off);

  if (lane < 16) {
    int c0 = (l & 1) * 4;
#pragma unroll
    for (int r = 0; r < 4; ++r) {
      int c = c0 + r;
      if (c < 7) out[(size_t)n * 56 + h2 * 7 + c] = acc[r] * inv_den + bias[h2 * 7 + c];
    }
  }
}

// ---------------- launch ----------------

extern "C" void kernel_launch(void* const* d_in, const int* in_sizes, int n_in,
                              void* d_out, int out_size, void* d_ws, size_t ws_size,
                              hipStream_t stream) {
  const float* x    = (const float*)d_in[0];
  const int*   ei   = (const int*)d_in[1];
  const float* W1   = (const float*)d_in[2];
  const float* at_s1 = (const float*)d_in[3];
  const float* at_d1 = (const float*)d_in[4];
  const float* b1   = (const float*)d_in[5];
  const float* W2   = (const float*)d_in[6];
  const float* at_s2 = (const float*)d_in[7];
  const float* at_d2 = (const float*)d_in[8];
  const float* b2   = (const float*)d_in[9];
  float* out = (float*)d_out;

  const int N = in_sizes[0] / 500;
  const int E = in_sizes[1] / 2;

  char* w = (char*)d_ws;
  auto alloc = [&](size_t bytes) -> void* {
    void* p = (void*)w;
    w += (bytes + 255) & ~(size_t)255;
    return p;
  };
  int*   rowptr = (int*)alloc((size_t)(N + 1) * 4);
  int*   cursor = (int*)alloc((size_t)N * 4);
  int*   deg    = (int*)alloc((size_t)N * 4);
  int*   flag   = (int*)alloc(256);
  int*   bsum   = (int*)alloc(4096);
  int*   boff   = (int*)alloc(4096);
  int*   ei_c   = (int*)alloc((size_t)2 * E * 4);
  int*   csr    = (int*)alloc((size_t)(E + N) * 4);
  float* o1     = (float*)alloc((size_t)N * 64 * 4);
  float* asb    = (float*)alloc((size_t)N * 8 * 4);
  float* adb    = (float*)alloc((size_t)N * 8 * 4);
  float* Wt2    = (float*)alloc((size_t)64 * 64 * 4);
  __bf16* Bhi1  = (__bf16*)alloc((size_t)32768 * 2);
  __bf16* Blo1  = (__bf16*)alloc((size_t)32768 * 2);
  __bf16* h1b   = (__bf16*)alloc((size_t)N * 64 * 2);  // layer-1 h bf16 [N,64]
  __bf16* h2b   = (__bf16*)alloc((size_t)N * 64 * 2);  // layer-2 h bf16 head-padded [N,64]

  auto cdiv = [](int a, int b) { return (a + b - 1) / b; };
  const int nbN = cdiv(N, 256);

  // CSR build (shared by both layers: same graph + self-loops)
  k_init<<<nbN, 256, 0, stream>>>(deg, flag, N);
  k_detect<<<cdiv(50000, 256), 256, 0, stream>>>(ei, flag, 50000);
  k_convert<<<cdiv(2 * E, 256), 256, 0, stream>>>(ei, flag, ei_c, deg, 2 * E, E);
  k_blocksum<<<nbN, 256, 0, stream>>>(deg, bsum, N);
  k_scan_bsum<<<1, 512, 0, stream>>>(bsum, boff, nbN, rowptr, N);
  k_scan_final<<<nbN, 256, 0, stream>>>(deg, boff, rowptr, cursor, N);
  {
    const int G = 768;
    k_fill_shard<<<8 * G, 256, 0, stream>>>(ei_c, cursor, csr, E, N, cdiv(E + N, G));
  }

  // Layer 1
  k_prep_b1<<<cdiv(32768, 256), 256, 0, stream>>>(W1, Bhi1, Blo1);
  k_gemm1_lds<<<cdiv(N, 64), 256, 0, stream>>>(x, (const bf16x8*)Bhi1, (const bf16x8*)Blo1, h1b, N);
  k_alpha_b<8><<<cdiv(N * 8, 256), 256, 0, stream>>>((const unsigned short*)h1b, at_s1, at_d1, asb, adb, N);
  k_agg1v<<<cdiv(N, 4), 256, 0, stream>>>((const unsigned short*)h1b, asb, adb, rowptr, csr, o1, N);

  // Layer 2 (bias b1 + ELU fused into GEMM2 input load)
  k_transpose_w<<<cdiv(64 * 64, 256), 256, 0, stream>>>(W2, Wt2, 56, 64, 64);
  k_gemm<true><<<cdiv(N, 128), 256, 0, stream>>>(o1, Wt2, b1, h2b, N, 64, 64, 56, 2);
  k_alpha_b<7><<<cdiv(N * 8, 256), 256, 0, stream>>>((const unsigned short*)h2b, at_s2, at_d2, asb, adb, N);
  k_agg2v<<<cdiv(N, 4), 256, 0, stream>>>((const unsigned short*)h2b, asb, adb, rowptr, csr, b2, out, N);
}

// Round 9
// 400.834 us; speedup vs baseline: 1.2891x; 1.0290x over previous
//
#include <hip/hip_runtime.h>

#define NEG_SLOPE 0.2f

typedef __bf16 bf16x8 __attribute__((ext_vector_type(8)));
typedef float f32x4 __attribute__((ext_vector_type(4)));

__device__ __forceinline__ float eluf(float x) { return x > 0.f ? x : __expf(x) - 1.f; }
__device__ __forceinline__ float lreluf(float x) { return x > 0.f ? x : NEG_SLOPE * x; }
__device__ __forceinline__ float bflo(unsigned u) { return __uint_as_float(u << 16); }
__device__ __forceinline__ float bfhi(unsigned u) { return __uint_as_float(u & 0xffff0000u); }

__device__ __forceinline__ void split8(const float4& p, const float4& q, bf16x8& hi, bf16x8& lo) {
  float v[8] = {p.x, p.y, p.z, p.w, q.x, q.y, q.z, q.w};
#pragma unroll
  for (int e = 0; e < 8; ++e) {
    __bf16 h = (__bf16)v[e];
    hi[e] = h;
    lo[e] = (__bf16)(v[e] - (float)h);
  }
}

// ---------------- CSR build ----------------

__global__ __launch_bounds__(256) void k_init(int* __restrict__ deg, int* __restrict__ flag, int N) {
  int i = blockIdx.x * 256 + threadIdx.x;
  if (i < N) deg[i] = 1;  // self-loop
  if (i == 0) *flag = 0;
}

// If edge_index arrived as int64, every odd int32 word is 0 (values < 2^31).
__global__ __launch_bounds__(256) void k_detect(const int* __restrict__ raw, int* __restrict__ flag, int nCheck) {
  int i = blockIdx.x * 256 + threadIdx.x;
  if (i < nCheck && raw[2 * i + 1] != 0) atomicOr(flag, 1);
}

// Convert (int64|int32) -> int32 AND count dst degrees (i >= E is the dst half).
__global__ __launch_bounds__(256) void k_convert(const int* __restrict__ raw, const int* __restrict__ flag,
                                                 int* __restrict__ out, int* __restrict__ deg, int n, int E) {
  int i = blockIdx.x * 256 + threadIdx.x;
  if (i >= n) return;
  bool is32 = (*flag != 0);
  int v = is32 ? raw[i] : raw[2 * i];
  out[i] = v;
  if (i >= E) atomicAdd(&deg[v], 1);
}

__global__ __launch_bounds__(256) void k_blocksum(const int* __restrict__ deg, int* __restrict__ bsum, int N) {
  __shared__ int s[256];
  int t = threadIdx.x;
  int i = blockIdx.x * 256 + t;
  s[t] = (i < N) ? deg[i] : 0;
  __syncthreads();
  for (int off = 128; off > 0; off >>= 1) {
    if (t < off) s[t] += s[t + off];
    __syncthreads();
  }
  if (t == 0) bsum[blockIdx.x] = s[0];
}

__global__ __launch_bounds__(512) void k_scan_bsum(const int* __restrict__ bsum, int* __restrict__ boff,
                                                   int nb, int* __restrict__ rowptr, int N) {
  __shared__ int s[512];
  int t = threadIdx.x;
  int v = (t < nb) ? bsum[t] : 0;
  s[t] = v;
  __syncthreads();
  for (int off = 1; off < 512; off <<= 1) {
    int u = (t >= off) ? s[t - off] : 0;
    __syncthreads();
    s[t] += u;
    __syncthreads();
  }
  if (t < nb) boff[t] = s[t] - v;       // exclusive
  if (t == nb - 1) rowptr[N] = s[t];    // total = E + N
}

__global__ __launch_bounds__(256) void k_scan_final(const int* __restrict__ deg, const int* __restrict__ boff,
                                                    int* __restrict__ rowptr, int* __restrict__ cursor, int N) {
  __shared__ int s[256];
  int t = threadIdx.x;
  int i = blockIdx.x * 256 + t;
  int v = (i < N) ? deg[i] : 0;
  s[t] = v;
  __syncthreads();
  for (int off = 1; off < 256; off <<= 1) {
    int u = (t >= off) ? s[t - off] : 0;
    __syncthreads();
    s[t] += u;
    __syncthreads();
  }
  if (i < N) {
    int ex = boff[blockIdx.x] + s[t] - v;
    rowptr[i] = ex;
    cursor[i] = ex;
  }
}

// XCD-sharded CSR fill (see R3): each XCD's csr writes stay in its own L2.
__global__ __launch_bounds__(256) void k_fill_shard(const int* __restrict__ ei, int* __restrict__ cursor,
                                                    int* __restrict__ csr, int E, int N, int CH) {
  const int shard = blockIdx.x & 7;
  const int chunk = blockIdx.x >> 3;
  const int i0 = chunk * CH;
  const int i1 = min(i0 + CH, E + N);
  for (int idx = i0 + (int)threadIdx.x; idx < i1; idx += 256) {
    int d = (idx < E) ? ei[E + idx] : idx - E;
    if (((d >> 13) & 7) != shard) continue;
    int s = (idx < E) ? ei[idx] : idx - E;
    int pos = atomicAdd(&cursor[d], 1);
    csr[pos] = s;
  }
}

// ---------------- weight prep (merged): W1^T MFMA fragments + W2^T pad ----------------

__global__ __launch_bounds__(256) void k_prep(const float* __restrict__ W1, __bf16* __restrict__ bhi,
                                              __bf16* __restrict__ blo,
                                              const float* __restrict__ W2, float* __restrict__ Wt2) {
  int idx = blockIdx.x * 256 + threadIdx.x;  // 128 blocks x 256
  if (idx < 32768) {
    int e = idx & 7;
    int lane = (idx >> 3) & 63;
    int nf = (idx >> 9) & 3;
    int ks = idx >> 11;
    int k = ks * 32 + (lane >> 4) * 8 + e;
    int col = nf * 16 + (lane & 15);
    float w = (k < 500) ? W1[(size_t)col * 500 + k] : 0.f;
    __bf16 h = (__bf16)w;
    bhi[idx] = h;
    blo[idx] = (__bf16)(w - (float)h);
  }
  if (idx < 4096) {  // Wt2[k][c] = W2[c][k], c<56 else 0
    int k = idx >> 6, c = idx & 63;
    Wt2[k * 64 + c] = (c < 56) ? W2[(size_t)c * 64 + k] : 0.f;
  }
}

// ---------------- layer-1 GEMM: split-bf16 MFMA, depth-2 async pipeline ----------------
// X (swizzled) AND B fragments staged via global_load_lds, 3 buffers, counted
// vmcnt (never 0 mid-loop) + raw s_barrier (T3/T4). No global loads in the
// loop body -> compiler's MFMA waits are lgkmcnt-only, prefetch stays in flight.
__global__ __launch_bounds__(256) void k_gemm1_lds(const float* __restrict__ X, const bf16x8* __restrict__ Bhi,
                                                   const bf16x8* __restrict__ Blo,
                                                   __bf16* __restrict__ outb, int M) {
  __shared__ __align__(16) float xs[3][2048];    // 3 x 8KB: X tile [64r x 32k] fp32, XOR-swizzled
  __shared__ __align__(16) __bf16 bs[3][4096];   // 3 x 8KB: B tile; hi at nf*512+lane*8, lo at +2048
  const int lane = threadIdx.x & 63;
  const int wid = threadIdx.x >> 6;
  const int row0 = blockIdx.x * 64;
  const int kgrp = lane >> 4;
  const int rloc = lane & 15;
  const int myrow = wid * 16 + rloc;

  const int ub = myrow * 128 + kgrp * 32;
  const int sw1 = (ub ^ ((myrow & 7) << 4)) >> 2;
  const int sw2 = ((ub + 16) ^ ((myrow & 7) << 4)) >> 2;

  int st_r[2], st_kf[2];
#pragma unroll
  for (int j = 0; j < 2; ++j) {
    int s = (wid * 2 + j) * 1024 + lane * 16;
    int r = s >> 7;
    int kb = (s & 127) ^ ((r & 7) << 4);
    st_r[j] = min(row0 + r, M - 1);  // clamp: over-read safe, C-write guarded
    st_kf[j] = kb >> 2;
  }

  auto stage = [&](int buf, int ks) {
    // X: 2 insts/wave (1KB each), swizzle-inverse on source, linear dest
#pragma unroll
    for (int j = 0; j < 2; ++j) {
      const float* src = X + (size_t)st_r[j] * 500 + ks * 32 + st_kf[j];
      __builtin_amdgcn_global_load_lds(
          (const __attribute__((address_space(1))) void*)src,
          (__attribute__((address_space(3))) void*)&xs[buf][(wid * 2 + j) * 256], 16, 0, 0);
    }
    // B: wave w stages nf=w, hi + lo (lane-linear 16B chunks)
    const bf16x8* sh = Bhi + (size_t)(ks * 4 + wid) * 64 + lane;
    const bf16x8* sl = Blo + (size_t)(ks * 4 + wid) * 64 + lane;
    __builtin_amdgcn_global_load_lds(
        (const __attribute__((address_space(1))) void*)sh,
        (__attribute__((address_space(3))) void*)&bs[buf][wid * 512], 16, 0, 0);
    __builtin_amdgcn_global_load_lds(
        (const __attribute__((address_space(1))) void*)sl,
        (__attribute__((address_space(3))) void*)&bs[buf][2048 + wid * 512], 16, 0, 0);
  };

  f32x4 acc[4];
#pragma unroll
  for (int nf = 0; nf < 4; ++nf) acc[nf] = (f32x4){0.f, 0.f, 0.f, 0.f};

  stage(0, 0);
  stage(1, 1);
  asm volatile("s_waitcnt vmcnt(4)" ::: "memory");  // tile 0 landed (4 loads of tile 1 in flight)
  __builtin_amdgcn_s_barrier();
  __builtin_amdgcn_sched_barrier(0);

  for (int ks = 0; ks < 15; ++ks) {
    if (ks < 13) stage((ks + 2) % 3, ks + 2);  // overwrites buffer (ks-1)%3: reads retired at prev barrier
    const int b = ks % 3;
    float4 p = *reinterpret_cast<const float4*>(&xs[b][sw1]);
    float4 q = *reinterpret_cast<const float4*>(&xs[b][sw2]);
    bf16x8 ah, al;
    split8(p, q, ah, al);
#pragma unroll
    for (int nf = 0; nf < 4; ++nf) {
      bf16x8 bh = *reinterpret_cast<const bf16x8*>(&bs[b][nf * 512 + lane * 8]);
      bf16x8 bl = *reinterpret_cast<const bf16x8*>(&bs[b][2048 + nf * 512 + lane * 8]);
      acc[nf] = __builtin_amdgcn_mfma_f32_16x16x32_bf16(ah, bh, acc[nf], 0, 0, 0);
      acc[nf] = __builtin_amdgcn_mfma_f32_16x16x32_bf16(al, bh, acc[nf], 0, 0, 0);
      acc[nf] = __builtin_amdgcn_mfma_f32_16x16x32_bf16(ah, bl, acc[nf], 0, 0, 0);
    }
    if (ks < 14) {
      if (ks < 13) asm volatile("s_waitcnt vmcnt(4)" ::: "memory");  // tile ks+1 landed, ks+2 in flight
      else         asm volatile("s_waitcnt vmcnt(0)" ::: "memory");  // drain (no more stages)
      __builtin_amdgcn_s_barrier();
      __builtin_amdgcn_sched_barrier(0);
    }
  }

  {  // ks = 15 tail (k = 480..499) from guarded register loads
    const bool rowok = row0 + myrow < M;
    const float* xrow = X + (size_t)(row0 + myrow) * 500;
    float v[8];
#pragma unroll
    for (int e = 0; e < 8; ++e) {
      int k = 480 + kgrp * 8 + e;
      v[e] = (rowok && k < 500) ? xrow[k] : 0.f;
    }
    bf16x8 ah, al;
#pragma unroll
    for (int e = 0; e < 8; ++e) {
      __bf16 h = (__bf16)v[e];
      ah[e] = h;
      al[e] = (__bf16)(v[e] - (float)h);
    }
#pragma unroll
    for (int nf = 0; nf < 4; ++nf) {
      bf16x8 bh = Bhi[(15 * 4 + nf) * 64 + lane];
      bf16x8 bl = Blo[(15 * 4 + nf) * 64 + lane];
      acc[nf] = __builtin_amdgcn_mfma_f32_16x16x32_bf16(ah, bh, acc[nf], 0, 0, 0);
      acc[nf] = __builtin_amdgcn_mfma_f32_16x16x32_bf16(al, bh, acc[nf], 0, 0, 0);
      acc[nf] = __builtin_amdgcn_mfma_f32_16x16x32_bf16(ah, bl, acc[nf], 0, 0, 0);
    }
  }

  const int colw = lane & 15;
#pragma unroll
  for (int r = 0; r < 4; ++r) {
    int rowd = row0 + wid * 16 + (lane >> 4) * 4 + r;
    if (rowd >= M) continue;
#pragma unroll
    for (int nf = 0; nf < 4; ++nf)
      outb[(size_t)rowd * 64 + nf * 16 + colw] = (__bf16)acc[nf][r];
  }
}

// ---------------- dense fp32 GEMM (layer 2) ----------------

// Layer-2 GEMM. Writes ONLY head-padded bf16 [M,64] (features h*8+c, pad c=7 zeroed).
template <bool ELU_IN>
__global__ __launch_bounds__(256) void k_gemm(const float* __restrict__ X, const float* __restrict__ Wt,
                                              const float* __restrict__ bias,
                                              __bf16* __restrict__ outb,
                                              int M, int K, int ldx, int OUTN, int ksteps) {
  __shared__ __align__(16) float xs[32][132];
  __shared__ __align__(16) float ws[32][64];
  const int t = threadIdx.x;
  const int rowg = t >> 4, colg = t & 15;
  const int brow = blockIdx.x * 128;
  float acc[8][4] = {};

  for (int ks = 0; ks < ksteps; ++ks) {
    const int k0 = ks * 32;
#pragma unroll
    for (int i = 0; i < 4; ++i) {
      int f = t + i * 256;
      int r = f >> 3, kq = f & 7;
      int grow = brow + r, gk = k0 + kq * 4;
      float4 v = {0.f, 0.f, 0.f, 0.f};
      if (grow < M && gk < K) {
        v = *reinterpret_cast<const float4*>(X + (size_t)grow * ldx + gk);
        if (ELU_IN) {
          v.x = eluf(v.x + bias[gk + 0]);
          v.y = eluf(v.y + bias[gk + 1]);
          v.z = eluf(v.z + bias[gk + 2]);
          v.w = eluf(v.w + bias[gk + 3]);
        }
      }
      xs[kq * 4 + 0][r] = v.x;
      xs[kq * 4 + 1][r] = v.y;
      xs[kq * 4 + 2][r] = v.z;
      xs[kq * 4 + 3][r] = v.w;
    }
#pragma unroll
    for (int i = 0; i < 2; ++i) {
      int f = t + i * 256;
      int kk = f >> 4, c4 = (f & 15) * 4;
      *reinterpret_cast<float4*>(&ws[kk][c4]) =
          *reinterpret_cast<const float4*>(Wt + (size_t)(k0 + kk) * 64 + c4);
    }
    __syncthreads();
#pragma unroll
    for (int k = 0; k < 32; ++k) {
      float4 xa = *reinterpret_cast<const float4*>(&xs[k][rowg * 8]);
      float4 xb = *reinterpret_cast<const float4*>(&xs[k][rowg * 8 + 4]);
      float4 wv = *reinterpret_cast<const float4*>(&ws[k][colg * 4]);
      float xr[8] = {xa.x, xa.y, xa.z, xa.w, xb.x, xb.y, xb.z, xb.w};
      float wc[4] = {wv.x, wv.y, wv.z, wv.w};
#pragma unroll
      for (int r = 0; r < 8; ++r)
#pragma unroll
        for (int c = 0; c < 4; ++c) acc[r][c] = fmaf(xr[r], wc[c], acc[r][c]);
    }
    __syncthreads();
  }

#pragma unroll
  for (int r = 0; r < 8; ++r) {
    int grow = brow + rowg * 8 + r;
    if (grow >= M) continue;
#pragma unroll
    for (int c = 0; c < 4; ++c) {
      int col = colg * 4 + c;
      if (col < OUTN) {
        int hh = col / 7, cc = col - hh * 7;
        outb[(size_t)grow * 64 + hh * 8 + cc] = (__bf16)acc[r][c];
      }
    }
    if (colg == 14) {  // zero the 8 pad slots (ws is 0xAA-poisoned)
#pragma unroll
      for (int hh = 0; hh < 8; ++hh) outb[(size_t)grow * 64 + hh * 8 + 7] = (__bf16)0.f;
    }
  }
}

// alpha from bf16 h rows (one uint4 = 8 slots per (node,head)); D = valid slots.
template <int D>
__global__ __launch_bounds__(256) void k_alpha_b(const unsigned short* __restrict__ hb,
                                                 const float* __restrict__ a_src,
                                                 const float* __restrict__ a_dst,
                                                 float* __restrict__ as_, float* __restrict__ ad_, int N) {
  int idx = blockIdx.x * 256 + threadIdx.x;
  int node = idx >> 3, head = idx & 7;
  if (node >= N) return;
  uint4 w = *reinterpret_cast<const uint4*>(hb + (size_t)node * 64 + head * 8);
  float v[8] = {bflo(w.x), bfhi(w.x), bflo(w.y), bfhi(w.y),
                bflo(w.z), bfhi(w.z), bflo(w.w), bfhi(w.w)};
  float ss = 0.f, sd = 0.f;
#pragma unroll
  for (int d = 0; d < D; ++d) {
    ss = fmaf(v[d], a_src[head * D + d], ss);
    sd = fmaf(v[d], a_dst[head * D + d], sd);
  }
  as_[idx] = ss;
  ad_[idx] = sd;
}

// Layer-1 aggregation: lane = (slot = lane>>3, head = lane&7).
// Pass A: max only (pure fmax chain, e buffered). Pass B: single exp/edge,
// den accumulated WITH acc and reduced in the same butterfly.
__global__ __launch_bounds__(256) void k_agg1v(const unsigned short* __restrict__ hb,
                                               const float* __restrict__ as_,
                                               const float* __restrict__ ad_,
                                               const int* __restrict__ rowptr,
                                               const int* __restrict__ csr,
                                               float* __restrict__ o1, int N) {
  const int lane = threadIdx.x & 63;
  const int n = blockIdx.x * 4 + (threadIdx.x >> 6);
  if (n >= N) return;
  const int r0 = rowptr[n], r1 = rowptr[n + 1];
  const int head = lane & 7;
  const int slot = lane >> 3;
  const float ad_h = ad_[(size_t)n * 8 + head];

  float m = -1e30f;
  float eb[6];
  int sb[6];
#pragma unroll
  for (int i = 0; i < 6; ++i) {
    int j = r0 + slot + i * 8;
    bool ok = j < r1;
    int s = ok ? csr[j] : 0;
    sb[i] = s;
    float e = lreluf(as_[(size_t)s * 8 + head] + ad_h);
    eb[i] = ok ? e : -1e30f;
    m = fmaxf(m, eb[i]);
  }
  for (int j = r0 + slot + 48; j < r1; j += 8)  // rare tail (deg > 48)
    m = fmaxf(m, lreluf(as_[(size_t)csr[j] * 8 + head] + ad_h));
#pragma unroll
  for (int off = 8; off < 64; off <<= 1) m = fmaxf(m, __shfl_xor(m, off));

  float den = 0.f;
  f32x4 accA = {0.f, 0.f, 0.f, 0.f}, accB = {0.f, 0.f, 0.f, 0.f};
#pragma unroll
  for (int i = 0; i < 6; ++i) {
    int j = r0 + slot + i * 8;
    if (j < r1) {
      float p = __expf(eb[i] - m);
      den += p;
      uint4 w = *reinterpret_cast<const uint4*>(hb + (size_t)sb[i] * 64 + head * 8);
      accA[0] = fmaf(p, bflo(w.x), accA[0]);
      accA[1] = fmaf(p, bfhi(w.x), accA[1]);
      accA[2] = fmaf(p, bflo(w.y), accA[2]);
      accA[3] = fmaf(p, bfhi(w.y), accA[3]);
      accB[0] = fmaf(p, bflo(w.z), accB[0]);
      accB[1] = fmaf(p, bfhi(w.z), accB[1]);
      accB[2] = fmaf(p, bflo(w.w), accB[2]);
      accB[3] = fmaf(p, bfhi(w.w), accB[3]);
    }
  }
  for (int j = r0 + slot + 48; j < r1; j += 8) {  // rare tail
    int s = csr[j];
    float p = __expf(lreluf(as_[(size_t)s * 8 + head] + ad_h) - m);
    den += p;
    uint4 w = *reinterpret_cast<const uint4*>(hb + (size_t)s * 64 + head * 8);
    accA[0] = fmaf(p, bflo(w.x), accA[0]);
    accA[1] = fmaf(p, bfhi(w.x), accA[1]);
    accA[2] = fmaf(p, bflo(w.y), accA[2]);
    accA[3] = fmaf(p, bfhi(w.y), accA[3]);
    accB[0] = fmaf(p, bflo(w.z), accB[0]);
    accB[1] = fmaf(p, bfhi(w.z), accB[1]);
    accB[2] = fmaf(p, bflo(w.w), accB[2]);
    accB[3] = fmaf(p, bfhi(w.w), accB[3]);
  }
#pragma unroll
  for (int off = 8; off < 64; off <<= 1) {
    den += __shfl_xor(den, off);
#pragma unroll
    for (int k = 0; k < 4; ++k) {
      accA[k] += __shfl_xor(accA[k], off);
      accB[k] += __shfl_xor(accB[k], off);
    }
  }
  if (lane < 8) {
    float inv_den = 1.f / den;
    float4 oA = {accA[0] * inv_den, accA[1] * inv_den, accA[2] * inv_den, accA[3] * inv_den};
    float4 oB = {accB[0] * inv_den, accB[1] * inv_den, accB[2] * inv_den, accB[3] * inv_den};
    *reinterpret_cast<float4*>(o1 + (size_t)n * 64 + lane * 8) = oA;
    *reinterpret_cast<float4*>(o1 + (size_t)n * 64 + lane * 8 + 4) = oB;
  }
}

// Layer-2 aggregation on head-padded bf16 h [N,64]. Same max-only / fused-den
// structure; lane = (slot = lane>>4, l = lane&15, head = l>>1), 2 lanes per
// (edge,head) duplicate the scalar math (same bytes). Butterfly xor 16,32.
__global__ __launch_bounds__(256) void k_agg2v(const unsigned short* __restrict__ hb,
                                               const float* __restrict__ as_,
                                               const float* __restrict__ ad_,
                                               const int* __restrict__ rowptr,
                                               const int* __restrict__ csr,
                                               const float* __restrict__ bias,
                                               float* __restrict__ out, int N) {
  const int lane = threadIdx.x & 63;
  const int n = blockIdx.x * 4 + (threadIdx.x >> 6);
  if (n >= N) return;
  const int r0 = rowptr[n], r1 = rowptr[n + 1];
  const int l = lane & 15, slot = lane >> 4, h2 = l >> 1;
  const float ad2 = ad_[(size_t)n * 8 + h2];

  float m = -1e30f;
  float eb[8];
  int sb[8];
#pragma unroll
  for (int i = 0; i < 8; ++i) {
    int j = r0 + slot + i * 4;
    bool ok = j < r1;
    int s = ok ? csr[j] : 0;
    sb[i] = s;
    float e = lreluf(as_[(size_t)s * 8 + h2] + ad2);
    eb[i] = ok ? e : -1e30f;
    m = fmaxf(m, eb[i]);
  }
  for (int j = r0 + slot + 32; j < r1; j += 4)  // rare tail (deg > 32)
    m = fmaxf(m, lreluf(as_[(size_t)csr[j] * 8 + h2] + ad2));
#pragma unroll
  for (int off = 16; off < 64; off <<= 1) m = fmaxf(m, __shfl_xor(m, off));

  float den = 0.f;
  f32x4 acc = {0.f, 0.f, 0.f, 0.f};
#pragma unroll
  for (int i = 0; i < 8; ++i) {
    int j = r0 + slot + i * 4;
    if (j < r1) {
      float p = __expf(eb[i] - m);
      den += p;
      uint2 w = *reinterpret_cast<const uint2*>(hb + (size_t)sb[i] * 64 + l * 4);
      acc[0] = fmaf(p, bflo(w.x), acc[0]);
      acc[1] = fmaf(p, bfhi(w.x), acc[1]);
      acc[2] = fmaf(p, bflo(w.y), acc[2]);
      acc[3] = fmaf(p, bfhi(w.y), acc[3]);
    }
  }
  for (int j = r0 + slot + 32; j < r1; j += 4) {  // rare tail
    int s = csr[j];
    float p = __expf(lreluf(as_[(size_t)s * 8 + h2] + ad2) - m);
    den += p;
    uint2 w = *reinterpret_cast<const uint2*>(hb + (size_t)s * 64 + l * 4);
    acc[0] = fmaf(p, bflo(w.x), acc[0]);
    acc[1] = fmaf(p, bfhi(w.x), acc[1]);
    acc[2] = fmaf(p, bflo(w.y), acc[2]);
    acc[3] = fmaf(p, bfhi(w.y), acc[3]);
  }
#pragma unroll
  for (int off = 16; off < 64; off <<= 1) {
    den += __shfl_xor(den, off);
#pragma unroll
    for (int k = 0; k < 4; ++k) acc[k] += __shfl_xor(acc[k], off);
  }

  if (lane < 16) {
    float inv_den = 1.f / den;
    int c0 = (l & 1) * 4;
#pragma unroll
    for (int r = 0; r < 4; ++r) {
      int c = c0 + r;
      if (c < 7) out[(size_t)n * 56 + h2 * 7 + c] = acc[r] * inv_den + bias[h2 * 7 + c];
    }
  }
}

// ---------------- launch ----------------

extern "C" void kernel_launch(void* const* d_in, const int* in_sizes, int n_in,
                              void* d_out, int out_size, void* d_ws, size_t ws_size,
                              hipStream_t stream) {
  const float* x    = (const float*)d_in[0];
  const int*   ei   = (const int*)d_in[1];
  const float* W1   = (const float*)d_in[2];
  const float* at_s1 = (const float*)d_in[3];
  const float* at_d1 = (const float*)d_in[4];
  const float* b1   = (const float*)d_in[5];
  const float* W2   = (const float*)d_in[6];
  const float* at_s2 = (const float*)d_in[7];
  const float* at_d2 = (const float*)d_in[8];
  const float* b2   = (const float*)d_in[9];
  float* out = (float*)d_out;

  const int N = in_sizes[0] / 500;
  const int E = in_sizes[1] / 2;

  char* w = (char*)d_ws;
  auto alloc = [&](size_t bytes) -> void* {
    void* p = (void*)w;
    w += (bytes + 255) & ~(size_t)255;
    return p;
  };
  int*   rowptr = (int*)alloc((size_t)(N + 1) * 4);
  int*   cursor = (int*)alloc((size_t)N * 4);
  int*   deg    = (int*)alloc((size_t)N * 4);
  int*   flag   = (int*)alloc(256);
  int*   bsum   = (int*)alloc(4096);
  int*   boff   = (int*)alloc(4096);
  int*   ei_c   = (int*)alloc((size_t)2 * E * 4);
  int*   csr    = (int*)alloc((size_t)(E + N) * 4);
  float* o1     = (float*)alloc((size_t)N * 64 * 4);
  float* asb    = (float*)alloc((size_t)N * 8 * 4);
  float* adb    = (float*)alloc((size_t)N * 8 * 4);
  float* Wt2    = (float*)alloc((size_t)64 * 64 * 4);
  __bf16* Bhi1  = (__bf16*)alloc((size_t)32768 * 2);
  __bf16* Blo1  = (__bf16*)alloc((size_t)32768 * 2);
  __bf16* h1b   = (__bf16*)alloc((size_t)N * 64 * 2);  // layer-1 h bf16 [N,64]
  __bf16* h2b   = (__bf16*)alloc((size_t)N * 64 * 2);  // layer-2 h bf16 head-padded [N,64]

  auto cdiv = [](int a, int b) { return (a + b - 1) / b; };
  const int nbN = cdiv(N, 256);

  // CSR build (shared by both layers: same graph + self-loops)
  k_init<<<nbN, 256, 0, stream>>>(deg, flag, N);
  k_detect<<<cdiv(50000, 256), 256, 0, stream>>>(ei, flag, 50000);
  k_convert<<<cdiv(2 * E, 256), 256, 0, stream>>>(ei, flag, ei_c, deg, 2 * E, E);
  k_blocksum<<<nbN, 256, 0, stream>>>(deg, bsum, N);
  k_scan_bsum<<<1, 512, 0, stream>>>(bsum, boff, nbN, rowptr, N);
  k_scan_final<<<nbN, 256, 0, stream>>>(deg, boff, rowptr, cursor, N);
  {
    const int G = 768;
    k_fill_shard<<<8 * G, 256, 0, stream>>>(ei_c, cursor, csr, E, N, cdiv(E + N, G));
  }

  // Layer 1
  k_prep<<<128, 256, 0, stream>>>(W1, Bhi1, Blo1, W2, Wt2);
  k_gemm1_lds<<<cdiv(N, 64), 256, 0, stream>>>(x, (const bf16x8*)Bhi1, (const bf16x8*)Blo1, h1b, N);
  k_alpha_b<8><<<cdiv(N * 8, 256), 256, 0, stream>>>((const unsigned short*)h1b, at_s1, at_d1, asb, adb, N);
  k_agg1v<<<cdiv(N, 4), 256, 0, stream>>>((const unsigned short*)h1b, asb, adb, rowptr, csr, o1, N);

  // Layer 2 (bias b1 + ELU fused into GEMM2 input load)
  k_gemm<true><<<cdiv(N, 128), 256, 0, stream>>>(o1, Wt2, b1, h2b, N, 64, 64, 56, 2);
  k_alpha_b<7><<<cdiv(N * 8, 256), 256, 0, stream>>>((const unsigned short*)h2b, at_s2, at_d2, asb, adb, N);
  k_agg2v<<<cdiv(N, 4), 256, 0, stream>>>((const unsigned short*)h2b, asb, adb, rowptr, csr, b2, out, N);
}

// Round 10
// 383.341 us; speedup vs baseline: 1.3479x; 1.0456x over previous
//
#include <hip/hip_runtime.h>

#define NEG_SLOPE 0.2f

typedef __bf16 bf16x8 __attribute__((ext_vector_type(8)));
typedef float f32x4 __attribute__((ext_vector_type(4)));

__device__ __forceinline__ float eluf(float x) { return x > 0.f ? x : __expf(x) - 1.f; }
__device__ __forceinline__ float lreluf(float x) { return x > 0.f ? x : NEG_SLOPE * x; }
__device__ __forceinline__ float bflo(unsigned u) { return __uint_as_float(u << 16); }
__device__ __forceinline__ float bfhi(unsigned u) { return __uint_as_float(u & 0xffff0000u); }

__device__ __forceinline__ void split8(const float4& p, const float4& q, bf16x8& hi, bf16x8& lo) {
  float v[8] = {p.x, p.y, p.z, p.w, q.x, q.y, q.z, q.w};
#pragma unroll
  for (int e = 0; e < 8; ++e) {
    __bf16 h = (__bf16)v[e];
    hi[e] = h;
    lo[e] = (__bf16)(v[e] - (float)h);
  }
}

// ---------------- CSR build ----------------

__global__ __launch_bounds__(256) void k_init(int* __restrict__ deg, int* __restrict__ flag, int N) {
  int i = blockIdx.x * 256 + threadIdx.x;
  if (i < N) deg[i] = 1;  // self-loop
  if (i == 0) *flag = 0;
}

// If edge_index arrived as int64, every odd int32 word is 0 (values < 2^31).
__global__ __launch_bounds__(256) void k_detect(const int* __restrict__ raw, int* __restrict__ flag, int nCheck) {
  int i = blockIdx.x * 256 + threadIdx.x;
  if (i < nCheck && raw[2 * i + 1] != 0) atomicOr(flag, 1);
}

// Convert (int64|int32) -> int32 AND count dst degrees (i >= E is the dst half).
__global__ __launch_bounds__(256) void k_convert(const int* __restrict__ raw, const int* __restrict__ flag,
                                                 int* __restrict__ out, int* __restrict__ deg, int n, int E) {
  int i = blockIdx.x * 256 + threadIdx.x;
  if (i >= n) return;
  bool is32 = (*flag != 0);
  int v = is32 ? raw[i] : raw[2 * i];
  out[i] = v;
  if (i >= E) atomicAdd(&deg[v], 1);
}

__global__ __launch_bounds__(256) void k_blocksum(const int* __restrict__ deg, int* __restrict__ bsum, int N) {
  __shared__ int s[256];
  int t = threadIdx.x;
  int i = blockIdx.x * 256 + t;
  s[t] = (i < N) ? deg[i] : 0;
  __syncthreads();
  for (int off = 128; off > 0; off >>= 1) {
    if (t < off) s[t] += s[t + off];
    __syncthreads();
  }
  if (t == 0) bsum[blockIdx.x] = s[0];
}

__global__ __launch_bounds__(512) void k_scan_bsum(const int* __restrict__ bsum, int* __restrict__ boff,
                                                   int nb, int* __restrict__ rowptr, int N) {
  __shared__ int s[512];
  int t = threadIdx.x;
  int v = (t < nb) ? bsum[t] : 0;
  s[t] = v;
  __syncthreads();
  for (int off = 1; off < 512; off <<= 1) {
    int u = (t >= off) ? s[t - off] : 0;
    __syncthreads();
    s[t] += u;
    __syncthreads();
  }
  if (t < nb) boff[t] = s[t] - v;       // exclusive
  if (t == nb - 1) rowptr[N] = s[t];    // total = E + N
}

__global__ __launch_bounds__(256) void k_scan_final(const int* __restrict__ deg, const int* __restrict__ boff,
                                                    int* __restrict__ rowptr, int* __restrict__ cursor, int N) {
  __shared__ int s[256];
  int t = threadIdx.x;
  int i = blockIdx.x * 256 + t;
  int v = (i < N) ? deg[i] : 0;
  s[t] = v;
  __syncthreads();
  for (int off = 1; off < 256; off <<= 1) {
    int u = (t >= off) ? s[t - off] : 0;
    __syncthreads();
    s[t] += u;
    __syncthreads();
  }
  if (i < N) {
    int ex = boff[blockIdx.x] + s[t] - v;
    rowptr[i] = ex;
    cursor[i] = ex;
  }
}

// XCD-sharded CSR fill (see R3): each XCD's csr writes stay in its own L2.
__global__ __launch_bounds__(256) void k_fill_shard(const int* __restrict__ ei, int* __restrict__ cursor,
                                                    int* __restrict__ csr, int E, int N, int CH) {
  const int shard = blockIdx.x & 7;
  const int chunk = blockIdx.x >> 3;
  const int i0 = chunk * CH;
  const int i1 = min(i0 + CH, E + N);
  for (int idx = i0 + (int)threadIdx.x; idx < i1; idx += 256) {
    int d = (idx < E) ? ei[E + idx] : idx - E;
    if (((d >> 13) & 7) != shard) continue;
    int s = (idx < E) ? ei[idx] : idx - E;
    int pos = atomicAdd(&cursor[d], 1);
    csr[pos] = s;
  }
}

// ---------------- weight prep: W1^T and W2^T MFMA fragments (hi/lo) ----------------

__global__ __launch_bounds__(256) void k_prep(const float* __restrict__ W1, __bf16* __restrict__ b1h,
                                              __bf16* __restrict__ b1l,
                                              const float* __restrict__ W2, __bf16* __restrict__ b2h,
                                              __bf16* __restrict__ b2l) {
  int idx = blockIdx.x * 256 + threadIdx.x;  // 128 blocks x 256
  if (idx < 32768) {  // W1 frags: 16 ks x 4 nf x 64 lanes x 8
    int e = idx & 7;
    int lane = (idx >> 3) & 63;
    int nf = (idx >> 9) & 3;
    int ks = idx >> 11;
    int k = ks * 32 + (lane >> 4) * 8 + e;
    int col = nf * 16 + (lane & 15);
    float w = (k < 500) ? W1[(size_t)col * 500 + k] : 0.f;
    __bf16 h = (__bf16)w;
    b1h[idx] = h;
    b1l[idx] = (__bf16)(w - (float)h);
  }
  if (idx < 4096) {  // W2 frags: 2 ks x 4 nf x 64 lanes x 8; cols 56..63 zero
    int e = idx & 7;
    int lane = (idx >> 3) & 63;
    int nf = (idx >> 9) & 3;
    int ks = idx >> 11;
    int k = ks * 32 + (lane >> 4) * 8 + e;
    int col = nf * 16 + (lane & 15);
    float w = (col < 56) ? W2[(size_t)col * 64 + k] : 0.f;
    __bf16 h = (__bf16)w;
    b2h[idx] = h;
    b2l[idx] = (__bf16)(w - (float)h);
  }
}

// ---------------- layer-1 GEMM: split-bf16 MFMA, depth-2 async pipeline ----------------
__global__ __launch_bounds__(256) void k_gemm1_lds(const float* __restrict__ X, const bf16x8* __restrict__ Bhi,
                                                   const bf16x8* __restrict__ Blo,
                                                   __bf16* __restrict__ outb, int M) {
  __shared__ __align__(16) float xs[3][2048];    // 3 x 8KB: X tile [64r x 32k] fp32, XOR-swizzled
  __shared__ __align__(16) __bf16 bs[3][4096];   // 3 x 8KB: B tile; hi at nf*512+lane*8, lo at +2048
  const int lane = threadIdx.x & 63;
  const int wid = threadIdx.x >> 6;
  const int row0 = blockIdx.x * 64;
  const int kgrp = lane >> 4;
  const int rloc = lane & 15;
  const int myrow = wid * 16 + rloc;

  const int ub = myrow * 128 + kgrp * 32;
  const int sw1 = (ub ^ ((myrow & 7) << 4)) >> 2;
  const int sw2 = ((ub + 16) ^ ((myrow & 7) << 4)) >> 2;

  int st_r[2], st_kf[2];
#pragma unroll
  for (int j = 0; j < 2; ++j) {
    int s = (wid * 2 + j) * 1024 + lane * 16;
    int r = s >> 7;
    int kb = (s & 127) ^ ((r & 7) << 4);
    st_r[j] = min(row0 + r, M - 1);  // clamp: over-read safe, C-write guarded
    st_kf[j] = kb >> 2;
  }

  auto stage = [&](int buf, int ks) {
#pragma unroll
    for (int j = 0; j < 2; ++j) {
      const float* src = X + (size_t)st_r[j] * 500 + ks * 32 + st_kf[j];
      __builtin_amdgcn_global_load_lds(
          (const __attribute__((address_space(1))) void*)src,
          (__attribute__((address_space(3))) void*)&xs[buf][(wid * 2 + j) * 256], 16, 0, 0);
    }
    const bf16x8* sh = Bhi + (size_t)(ks * 4 + wid) * 64 + lane;
    const bf16x8* sl = Blo + (size_t)(ks * 4 + wid) * 64 + lane;
    __builtin_amdgcn_global_load_lds(
        (const __attribute__((address_space(1))) void*)sh,
        (__attribute__((address_space(3))) void*)&bs[buf][wid * 512], 16, 0, 0);
    __builtin_amdgcn_global_load_lds(
        (const __attribute__((address_space(1))) void*)sl,
        (__attribute__((address_space(3))) void*)&bs[buf][2048 + wid * 512], 16, 0, 0);
  };

  f32x4 acc[4];
#pragma unroll
  for (int nf = 0; nf < 4; ++nf) acc[nf] = (f32x4){0.f, 0.f, 0.f, 0.f};

  stage(0, 0);
  stage(1, 1);
  asm volatile("s_waitcnt vmcnt(4)" ::: "memory");
  __builtin_amdgcn_s_barrier();
  __builtin_amdgcn_sched_barrier(0);

  for (int ks = 0; ks < 15; ++ks) {
    if (ks < 13) stage((ks + 2) % 3, ks + 2);
    const int b = ks % 3;
    float4 p = *reinterpret_cast<const float4*>(&xs[b][sw1]);
    float4 q = *reinterpret_cast<const float4*>(&xs[b][sw2]);
    bf16x8 ah, al;
    split8(p, q, ah, al);
#pragma unroll
    for (int nf = 0; nf < 4; ++nf) {
      bf16x8 bh = *reinterpret_cast<const bf16x8*>(&bs[b][nf * 512 + lane * 8]);
      bf16x8 bl = *reinterpret_cast<const bf16x8*>(&bs[b][2048 + nf * 512 + lane * 8]);
      acc[nf] = __builtin_amdgcn_mfma_f32_16x16x32_bf16(ah, bh, acc[nf], 0, 0, 0);
      acc[nf] = __builtin_amdgcn_mfma_f32_16x16x32_bf16(al, bh, acc[nf], 0, 0, 0);
      acc[nf] = __builtin_amdgcn_mfma_f32_16x16x32_bf16(ah, bl, acc[nf], 0, 0, 0);
    }
    if (ks < 14) {
      if (ks < 13) asm volatile("s_waitcnt vmcnt(4)" ::: "memory");
      else         asm volatile("s_waitcnt vmcnt(0)" ::: "memory");
      __builtin_amdgcn_s_barrier();
      __builtin_amdgcn_sched_barrier(0);
    }
  }

  {  // ks = 15 tail (k = 480..499) from guarded register loads
    const bool rowok = row0 + myrow < M;
    const float* xrow = X + (size_t)(row0 + myrow) * 500;
    float v[8];
#pragma unroll
    for (int e = 0; e < 8; ++e) {
      int k = 480 + kgrp * 8 + e;
      v[e] = (rowok && k < 500) ? xrow[k] : 0.f;
    }
    bf16x8 ah, al;
#pragma unroll
    for (int e = 0; e < 8; ++e) {
      __bf16 h = (__bf16)v[e];
      ah[e] = h;
      al[e] = (__bf16)(v[e] - (float)h);
    }
#pragma unroll
    for (int nf = 0; nf < 4; ++nf) {
      bf16x8 bh = Bhi[(15 * 4 + nf) * 64 + lane];
      bf16x8 bl = Blo[(15 * 4 + nf) * 64 + lane];
      acc[nf] = __builtin_amdgcn_mfma_f32_16x16x32_bf16(ah, bh, acc[nf], 0, 0, 0);
      acc[nf] = __builtin_amdgcn_mfma_f32_16x16x32_bf16(al, bh, acc[nf], 0, 0, 0);
      acc[nf] = __builtin_amdgcn_mfma_f32_16x16x32_bf16(ah, bl, acc[nf], 0, 0, 0);
    }
  }

  const int colw = lane & 15;
#pragma unroll
  for (int r = 0; r < 4; ++r) {
    int rowd = row0 + wid * 16 + (lane >> 4) * 4 + r;
    if (rowd >= M) continue;
#pragma unroll
    for (int nf = 0; nf < 4; ++nf)
      outb[(size_t)rowd * 64 + nf * 16 + colw] = (__bf16)acc[nf][r];
  }
}

// ---------------- layer-2 GEMM: split-bf16 MFMA, single-stage LDS ----------------
// X = elu'd layer-2 input as bf16 hi/lo [N,64] (written by k_agg1v).
// Output: head-padded bf16 [M,64] (slot h*8+c for col h*7+c; pads zeroed).
__global__ __launch_bounds__(256) void k_gemm2_mfma(const __bf16* __restrict__ Xh, const __bf16* __restrict__ Xl,
                                                    const bf16x8* __restrict__ B2h, const bf16x8* __restrict__ B2l,
                                                    __bf16* __restrict__ outb, int M) {
  __shared__ __align__(16) __bf16 xh[4096], xl[4096];  // 8KB each, XOR-swizzled
  const int lane = threadIdx.x & 63;
  const int wid = threadIdx.x >> 6;
  const int row0 = blockIdx.x * 64;
  const int kgrp = lane >> 4;
  const int rloc = lane & 15;
  const int myrow = wid * 16 + rloc;

#pragma unroll
  for (int j = 0; j < 4; ++j) {
    int chunk = wid * 4 + j;          // 0..15: 0-7 hi, 8-15 lo
    bool lo = chunk >= 8;
    int s = (chunk & 7) * 1024 + lane * 16;  // byte offset in 8KB buffer
    int r = s >> 7;
    int kb = (s & 127) ^ ((r & 7) << 4);
    int rg = min(row0 + r, M - 1);
    const __bf16* src = (lo ? Xl : Xh) + (size_t)rg * 64 + (kb >> 1);
    __bf16* dstbase = (lo ? xl : xh) + (chunk & 7) * 512;
    __builtin_amdgcn_global_load_lds(
        (const __attribute__((address_space(1))) void*)src,
        (__attribute__((address_space(3))) void*)dstbase, 16, 0, 0);
  }
  __syncthreads();

  f32x4 acc[4];
#pragma unroll
  for (int nf = 0; nf < 4; ++nf) acc[nf] = (f32x4){0.f, 0.f, 0.f, 0.f};

#pragma unroll
  for (int ks = 0; ks < 2; ++ks) {
    int ub = myrow * 128 + ks * 64 + kgrp * 16;
    int sw = (ub ^ ((myrow & 7) << 4)) >> 1;  // bf16 index
    bf16x8 ah = *reinterpret_cast<const bf16x8*>(&xh[sw]);
    bf16x8 al = *reinterpret_cast<const bf16x8*>(&xl[sw]);
#pragma unroll
    for (int nf = 0; nf < 4; ++nf) {
      bf16x8 bh = B2h[(ks * 4 + nf) * 64 + lane];
      bf16x8 bl = B2l[(ks * 4 + nf) * 64 + lane];
      acc[nf] = __builtin_amdgcn_mfma_f32_16x16x32_bf16(ah, bh, acc[nf], 0, 0, 0);
      acc[nf] = __builtin_amdgcn_mfma_f32_16x16x32_bf16(al, bh, acc[nf], 0, 0, 0);
      acc[nf] = __builtin_amdgcn_mfma_f32_16x16x32_bf16(ah, bl, acc[nf], 0, 0, 0);
    }
  }

  const int colw = lane & 15;
#pragma unroll
  for (int r = 0; r < 4; ++r) {
    int rowd = row0 + wid * 16 + (lane >> 4) * 4 + r;
    if (rowd >= M) continue;
#pragma unroll
    for (int nf = 0; nf < 4; ++nf) {
      int col = nf * 16 + colw;
      if (col < 56) {
        int hh = col / 7, cc = col - hh * 7;
        outb[(size_t)rowd * 64 + hh * 8 + cc] = (__bf16)acc[nf][r];
      } else {
        outb[(size_t)rowd * 64 + (col - 56) * 8 + 7] = (__bf16)0.f;  // pad slot
      }
    }
  }
}

// alpha from bf16 h rows (one uint4 = 8 slots per (node,head)); D = valid slots.
template <int D>
__global__ __launch_bounds__(256) void k_alpha_b(const unsigned short* __restrict__ hb,
                                                 const float* __restrict__ a_src,
                                                 const float* __restrict__ a_dst,
                                                 float* __restrict__ as_, float* __restrict__ ad_, int N) {
  int idx = blockIdx.x * 256 + threadIdx.x;
  int node = idx >> 3, head = idx & 7;
  if (node >= N) return;
  uint4 w = *reinterpret_cast<const uint4*>(hb + (size_t)node * 64 + head * 8);
  float v[8] = {bflo(w.x), bfhi(w.x), bflo(w.y), bfhi(w.y),
                bflo(w.z), bfhi(w.z), bflo(w.w), bfhi(w.w)};
  float ss = 0.f, sd = 0.f;
#pragma unroll
  for (int d = 0; d < D; ++d) {
    ss = fmaf(v[d], a_src[head * D + d], ss);
    sd = fmaf(v[d], a_dst[head * D + d], sd);
  }
  as_[idx] = ss;
  ad_[idx] = sd;
}

// Layer-1 aggregation, SINGLE PASS (m=0 softmax — logits bounded, shift-invariant).
// lane = (slot = lane>>3, head = lane&7); 8 edges/iter; den fused with acc.
// Epilogue applies +b1, ELU, and writes bf16 hi/lo (layer-2 GEMM input).
__global__ __launch_bounds__(256) void k_agg1v(const unsigned short* __restrict__ hb,
                                               const float* __restrict__ as_,
                                               const float* __restrict__ ad_,
                                               const int* __restrict__ rowptr,
                                               const int* __restrict__ csr,
                                               const float* __restrict__ b1,
                                               __bf16* __restrict__ oh, __bf16* __restrict__ ol, int N) {
  const int lane = threadIdx.x & 63;
  const int n = blockIdx.x * 4 + (threadIdx.x >> 6);
  if (n >= N) return;
  const int r0 = rowptr[n], r1 = rowptr[n + 1];
  const int head = lane & 7;
  const int slot = lane >> 3;
  const float ad_h = ad_[(size_t)n * 8 + head];

  float den = 0.f;
  f32x4 accA = {0.f, 0.f, 0.f, 0.f}, accB = {0.f, 0.f, 0.f, 0.f};
  for (int j = r0 + slot; j < r1; j += 8) {
    int s = csr[j];
    float p = __expf(lreluf(as_[(size_t)s * 8 + head] + ad_h));
    den += p;
    uint4 w = *reinterpret_cast<const uint4*>(hb + (size_t)s * 64 + head * 8);
    accA[0] = fmaf(p, bflo(w.x), accA[0]);
    accA[1] = fmaf(p, bfhi(w.x), accA[1]);
    accA[2] = fmaf(p, bflo(w.y), accA[2]);
    accA[3] = fmaf(p, bfhi(w.y), accA[3]);
    accB[0] = fmaf(p, bflo(w.z), accB[0]);
    accB[1] = fmaf(p, bfhi(w.z), accB[1]);
    accB[2] = fmaf(p, bflo(w.w), accB[2]);
    accB[3] = fmaf(p, bfhi(w.w), accB[3]);
  }
#pragma unroll
  for (int off = 8; off < 64; off <<= 1) {
    den += __shfl_xor(den, off);
#pragma unroll
    for (int k = 0; k < 4; ++k) {
      accA[k] += __shfl_xor(accA[k], off);
      accB[k] += __shfl_xor(accB[k], off);
    }
  }
  if (lane < 8) {
    float inv_den = 1.f / den;
    float o[8];
#pragma unroll
    for (int k = 0; k < 4; ++k) {
      o[k] = eluf(accA[k] * inv_den + b1[lane * 8 + k]);
      o[4 + k] = eluf(accB[k] * inv_den + b1[lane * 8 + 4 + k]);
    }
    bf16x8 vh, vl;
#pragma unroll
    for (int k = 0; k < 8; ++k) {
      __bf16 h = (__bf16)o[k];
      vh[k] = h;
      vl[k] = (__bf16)(o[k] - (float)h);
    }
    *reinterpret_cast<bf16x8*>(oh + (size_t)n * 64 + lane * 8) = vh;
    *reinterpret_cast<bf16x8*>(ol + (size_t)n * 64 + lane * 8) = vl;
  }
}

// Layer-2 aggregation, SINGLE PASS (m=0). lane = (slot = lane>>4, l = lane&15,
// head = l>>1); 2 lanes duplicate scalar math per (edge,head) — same bytes.
// Butterfly xor 16,32 merges the 4 slots. Output [N,56] + bias.
__global__ __launch_bounds__(256) void k_agg2v(const unsigned short* __restrict__ hb,
                                               const float* __restrict__ as_,
                                               const float* __restrict__ ad_,
                                               const int* __restrict__ rowptr,
                                               const int* __restrict__ csr,
                                               const float* __restrict__ bias,
                                               float* __restrict__ out, int N) {
  const int lane = threadIdx.x & 63;
  const int n = blockIdx.x * 4 + (threadIdx.x >> 6);
  if (n >= N) return;
  const int r0 = rowptr[n], r1 = rowptr[n + 1];
  const int l = lane & 15, slot = lane >> 4, h2 = l >> 1;
  const float ad2 = ad_[(size_t)n * 8 + h2];

  float den = 0.f;
  f32x4 acc = {0.f, 0.f, 0.f, 0.f};
  for (int j = r0 + slot; j < r1; j += 4) {
    int s = csr[j];
    float p = __expf(lreluf(as_[(size_t)s * 8 + h2] + ad2));
    den += p;
    uint2 w = *reinterpret_cast<const uint2*>(hb + (size_t)s * 64 + l * 4);
    acc[0] = fmaf(p, bflo(w.x), acc[0]);
    acc[1] = fmaf(p, bfhi(w.x), acc[1]);
    acc[2] = fmaf(p, bflo(w.y), acc[2]);
    acc[3] = fmaf(p, bfhi(w.y), acc[3]);
  }
#pragma unroll
  for (int off = 16; off < 64; off <<= 1) {
    den += __shfl_xor(den, off);
#pragma unroll
    for (int k = 0; k < 4; ++k) acc[k] += __shfl_xor(acc[k], off);
  }

  if (lane < 16) {
    float inv_den = 1.f / den;
    int c0 = (l & 1) * 4;
#pragma unroll
    for (int r = 0; r < 4; ++r) {
      int c = c0 + r;
      if (c < 7) out[(size_t)n * 56 + h2 * 7 + c] = acc[r] * inv_den + bias[h2 * 7 + c];
    }
  }
}

// ---------------- launch ----------------

extern "C" void kernel_launch(void* const* d_in, const int* in_sizes, int n_in,
                              void* d_out, int out_size, void* d_ws, size_t ws_size,
                              hipStream_t stream) {
  const float* x    = (const float*)d_in[0];
  const int*   ei   = (const int*)d_in[1];
  const float* W1   = (const float*)d_in[2];
  const float* at_s1 = (const float*)d_in[3];
  const float* at_d1 = (const float*)d_in[4];
  const float* b1   = (const float*)d_in[5];
  const float* W2   = (const float*)d_in[6];
  const float* at_s2 = (const float*)d_in[7];
  const float* at_d2 = (const float*)d_in[8];
  const float* b2   = (const float*)d_in[9];
  float* out = (float*)d_out;

  const int N = in_sizes[0] / 500;
  const int E = in_sizes[1] / 2;

  char* w = (char*)d_ws;
  auto alloc = [&](size_t bytes) -> void* {
    void* p = (void*)w;
    w += (bytes + 255) & ~(size_t)255;
    return p;
  };
  int*   rowptr = (int*)alloc((size_t)(N + 1) * 4);
  int*   cursor = (int*)alloc((size_t)N * 4);
  int*   deg    = (int*)alloc((size_t)N * 4);
  int*   flag   = (int*)alloc(256);
  int*   bsum   = (int*)alloc(4096);
  int*   boff   = (int*)alloc(4096);
  int*   ei_c   = (int*)alloc((size_t)2 * E * 4);
  int*   csr    = (int*)alloc((size_t)(E + N) * 4);
  float* asb    = (float*)alloc((size_t)N * 8 * 4);
  float* adb    = (float*)alloc((size_t)N * 8 * 4);
  __bf16* B1h   = (__bf16*)alloc((size_t)32768 * 2);
  __bf16* B1l   = (__bf16*)alloc((size_t)32768 * 2);
  __bf16* B2h   = (__bf16*)alloc((size_t)4096 * 2);
  __bf16* B2l   = (__bf16*)alloc((size_t)4096 * 2);
  __bf16* h1b   = (__bf16*)alloc((size_t)N * 64 * 2);  // layer-1 h bf16 [N,64]
  __bf16* o1h   = (__bf16*)alloc((size_t)N * 64 * 2);  // elu(agg1+b1) hi
  __bf16* o1l   = (__bf16*)alloc((size_t)N * 64 * 2);  // elu(agg1+b1) lo
  __bf16* h2b   = (__bf16*)alloc((size_t)N * 64 * 2);  // layer-2 h bf16 head-padded [N,64]

  auto cdiv = [](int a, int b) { return (a + b - 1) / b; };
  const int nbN = cdiv(N, 256);

  // CSR build (shared by both layers: same graph + self-loops)
  k_init<<<nbN, 256, 0, stream>>>(deg, flag, N);
  k_detect<<<cdiv(50000, 256), 256, 0, stream>>>(ei, flag, 50000);
  k_convert<<<cdiv(2 * E, 256), 256, 0, stream>>>(ei, flag, ei_c, deg, 2 * E, E);
  k_blocksum<<<nbN, 256, 0, stream>>>(deg, bsum, N);
  k_scan_bsum<<<1, 512, 0, stream>>>(bsum, boff, nbN, rowptr, N);
  k_scan_final<<<nbN, 256, 0, stream>>>(deg, boff, rowptr, cursor, N);
  {
    const int G = 768;
    k_fill_shard<<<8 * G, 256, 0, stream>>>(ei_c, cursor, csr, E, N, cdiv(E + N, G));
  }

  // Layer 1
  k_prep<<<128, 256, 0, stream>>>(W1, B1h, B1l, W2, B2h, B2l);
  k_gemm1_lds<<<cdiv(N, 64), 256, 0, stream>>>(x, (const bf16x8*)B1h, (const bf16x8*)B1l, h1b, N);
  k_alpha_b<8><<<cdiv(N * 8, 256), 256, 0, stream>>>((const unsigned short*)h1b, at_s1, at_d1, asb, adb, N);
  k_agg1v<<<cdiv(N, 4), 256, 0, stream>>>((const unsigned short*)h1b, asb, adb, rowptr, csr, b1, o1h, o1l, N);

  // Layer 2
  k_gemm2_mfma<<<cdiv(N, 64), 256, 0, stream>>>(o1h, o1l, (const bf16x8*)B2h, (const bf16x8*)B2l, h2b, N);
  k_alpha_b<7><<<cdiv(N * 8, 256), 256, 0, stream>>>((const unsigned short*)h2b, at_s2, at_d2, asb, adb, N);
  k_agg2v<<<cdiv(N, 4), 256, 0, stream>>>((const unsigned short*)h2b, asb, adb, rowptr, csr, b2, out, N);
}